// Round 10
// baseline (249.777 us; speedup 1.0000x reference)
//
#include <hip/hip_runtime.h>
#include <hip/hip_bf16.h>
#include <math.h>

typedef __bf16 bf16x8 __attribute__((ext_vector_type(8)));
typedef float f32x4 __attribute__((ext_vector_type(4)));
typedef unsigned int u32;
typedef u32 u32x4 __attribute__((ext_vector_type(4)));
typedef u32 u32x2 __attribute__((ext_vector_type(2)));

// Problem constants: B=8, C=256, H=W=64, O=256, K=9, GN groups=32 (8 ch each)
// xT layout (granule-major): [b][cg=32][pix=4096][8ch] bf16; granule = 16B.

__device__ inline u32 pack2bf16(float a, float b) {
  u32 ua = __float_as_uint(a);
  u32 ub = __float_as_uint(b);
  ua += 0x7fffu + ((ua >> 16) & 1u);   // RNE
  ub += 0x7fffu + ((ub >> 16) & 1u);
  return (ua >> 16) | (ub & 0xffff0000u);
}

// ---------------------------------------------------------------------------
// K0: prep — pack w_dcn into swizzled bf16 tiles, pack w_off into swizzled
// bf16 tiles (O padded 18->32), zero stats.
// ---------------------------------------------------------------------------
__global__ void prep(const float* __restrict__ w_dcn, const float* __restrict__ w_off,
                     unsigned short* __restrict__ wT4, unsigned short* __restrict__ wOffT,
                     float* __restrict__ stats) {
  size_t id = (size_t)blockIdx.x * 256 + threadIdx.x;
  if (id < 589824) {               // 256 o * 2304 ck
    int o  = (int)(id / 2304);
    int ck = (int)(id % 2304);     // ck = k*256 + c
    int k = ck >> 8, c = ck & 255;
    float v = w_dcn[(size_t)(o * 256 + c) * 9 + k];
    u32 uv = __float_as_uint(v);
    uv += 0x7fffu + ((uv >> 16) & 1u);
    int tile = ck >> 6, kk = ck & 63;
    int lin = o * 128 + kk * 2;
    int swz = lin ^ ((o & 7) << 4);
    *(unsigned short*)((char*)wT4 + (size_t)tile * 32768 + swz) = (unsigned short)(uv >> 16);
  } else if (id < 663552) {        // 36 tiles * 32 o * 64 kk = 73728
    int r = (int)(id - 589824);
    int tile = r >> 11;            // k*4 + cc
    int rr = r & 2047;
    int o = rr >> 6, kk = rr & 63;
    int k = tile >> 2, cc = tile & 3;
    int c = (cc << 6) + kk;
    float v = (o < 18) ? w_off[(size_t)(o * 256 + c) * 9 + k] : 0.f;
    u32 uv = __float_as_uint(v);
    uv += 0x7fffu + ((uv >> 16) & 1u);
    int swz = (o * 128 + kk * 2) ^ ((o & 7) << 4);
    *(unsigned short*)((char*)wOffT + (size_t)tile * 4096 + swz) = (unsigned short)(uv >> 16);
  } else if (id < 664064) {        // zero stats: 512 floats
    stats[id - 663552] = 0.f;
  }
}

// ---------------------------------------------------------------------------
// K1: transpose x [B][C][H][W] -> xT granule-major [b][cg][pix][8ch] bf16
// ---------------------------------------------------------------------------
__global__ __launch_bounds__(256) void transpose_x(const float* __restrict__ x,
                                                   unsigned short* __restrict__ xT) {
  __shared__ float tl[64][65];
  int bx = blockIdx.x;
  int b = bx >> 8;
  int y = (bx >> 2) & 63;
  int cb = (bx & 3) << 6;          // 64-ch chunk base
  int t = threadIdx.x;
  int xi = t & 63, cr = t >> 6;
  size_t base = (((size_t)(b * 256 + cb) * 64 + y) << 6);
#pragma unroll
  for (int rep = 0; rep < 16; ++rep) {
    int cl = rep * 4 + cr;
    tl[cl][xi] = x[base + (size_t)cl * 4096 + xi];
  }
  __syncthreads();
  int xw = t & 63, cpair = t >> 6;   // cpair in [0,4)
#pragma unroll
  for (int r = 0; r < 2; ++r) {
    int cgl = cpair * 2 + r;         // local granule in this 64-ch chunk
    int cg = (cb >> 3) + cgl;
    u32 pk4[4];
#pragma unroll
    for (int i = 0; i < 4; ++i)
      pk4[i] = pack2bf16(tl[cgl * 8 + 2 * i][xw], tl[cgl * 8 + 2 * i + 1][xw]);
    u32x4 v = {pk4[0], pk4[1], pk4[2], pk4[3]};
    *(u32x4*)((char*)xT + (((size_t)b << 21)) + ((size_t)cg << 16) + ((y << 6) + xw) * 16) = v;
  }
}

// ---------------------------------------------------------------------------
// K2: offset conv via MFMA (unchanged from R9).
// ---------------------------------------------------------------------------
__global__ __launch_bounds__(512, 2) void conv_offset_mfma(
    const unsigned short* __restrict__ xT, const unsigned short* __restrict__ wOffT,
    float* __restrict__ offs) {
  __shared__ unsigned short A[2][128][64]; // 32KB, byte ^= (row&7)<<4
  __shared__ unsigned short Bo[2][2048];   // 8KB  ([32 o][64 kk], swizzled)
  const int bx = blockIdx.x;
  const int lb = ((bx & 7) << 5) + (bx >> 3);   // XCD x -> image x
  const int b = lb >> 5;
  const int rp = lb & 31;          // row pair
  const int t = threadIdx.x;
  const int lane = t & 63, wid = t >> 6;   // wid 0..7
  const char* xTbB = (const char*)xT + ((size_t)b << 21);
  const int p = t >> 2;            // local pixel 0..127
  const int row = (rp << 1) + (p >> 6);
  const int xx = p & 63;
  const int cpl = (t & 3) << 1;    // granule-pair slot within cc-chunk

  f32x4 acc[2];
  {
    f32x4 z = {0.f, 0.f, 0.f, 0.f};
    acc[0] = z; acc[1] = z;
  }

  u32x4 ra = {0u,0u,0u,0u}, rb = {0u,0u,0u,0u};

  auto issue = [&](int tt, int d) {
    int k = tt >> 2, cc = tt & 3;
    int ky = k / 3, kx = k - ky * 3;
    int ys = row - 1 + ky;
    int xs = xx - 1 + kx;
    bool ok = ((unsigned)ys < 64u) && ((unsigned)xs < 64u);
    u32x4 z = {0u,0u,0u,0u};
    ra = z; rb = z;
    if (ok) {
      const char* s0 = xTbB + ((size_t)(cc * 8 + cpl) << 16) + (((ys << 6) + xs) << 4);
      ra = *(const u32x4*)s0;
      rb = *(const u32x4*)(s0 + 65536);
    }
    if (wid < 4)
      __builtin_amdgcn_global_load_lds(
          (const __attribute__((address_space(1))) u32*)((const char*)wOffT + ((size_t)tt << 12) + (wid << 10) + (lane << 4)),
          (__attribute__((address_space(3))) u32*)((char*)&Bo[d][0] + (wid << 10)),
          16, 0, 0);
  };
  auto writeA = [&](int d) {
    char* dst = (char*)&A[d][0][0] + p * 128;
    int b0 = (t & 3) << 5;
    int sw = (p & 7) << 4;
    *(u32x4*)(dst + (b0 ^ sw)) = ra;
    *(u32x4*)(dst + ((b0 + 16) ^ sw)) = rb;
  };

  issue(0, 0);
  writeA(0);
  __syncthreads();

  int cur = 0;
  for (int tt = 0; tt < 36; ++tt) {
    if (tt < 35) issue(tt + 1, cur ^ 1);
#pragma unroll
    for (int s = 0; s < 2; ++s) {
      int r16 = (wid << 4) + (lane & 15);
      int kx = (s << 6) + ((lane >> 4) << 4);
      bf16x8 a = *(const bf16x8*)((const char*)&A[cur][0][0] + r16 * 128 + (kx ^ ((r16 & 7) << 4)));
#pragma unroll
      for (int j = 0; j < 2; ++j) {
        int o = (j << 4) + (lane & 15);
        bf16x8 bv = *(const bf16x8*)((const char*)&Bo[cur][0] + o * 128 + (kx ^ ((o & 7) << 4)));
        acc[j] = __builtin_amdgcn_mfma_f32_16x16x32_bf16(a, bv, acc[j], 0, 0, 0);
      }
    }
    if (tt < 35) writeA(cur ^ 1);
    __syncthreads();
    cur ^= 1;
  }

#pragma unroll
  for (int j = 0; j < 2; ++j) {
    int o = (j << 4) + (lane & 15);
    if (o < 18) {
#pragma unroll
      for (int r = 0; r < 4; ++r) {
        int pl = (wid << 4) + ((lane >> 4) << 2) + r;
        offs[((size_t)b * 4096 + (rp << 7) + pl) * 18 + o] = acc[j][r];
      }
    }
  }
}

// ---------------------------------------------------------------------------
// K4: main fused kernel — A-FRAGMENTS IN REGISTERS (no A LDS at all).
// MFMA A-frag layout = lane(px=l&15) x granule(l>>4) == one sampled granule:
// each lane bilinear-samples directly into the operand register.
// block = 64 px x 256 O, 256 thr, 4 waves (wave = 64px x 64o, acc[4][4]).
// LDS: only B dbuf 2x32KB = 64KB -> 2 blocks/CU. B-slice read exactly once
// per block per step -> per-CU LDS traffic ~halved vs R9.
// ---------------------------------------------------------------------------
union ArenaU {
  unsigned short Bt[2][16384];     // 65,536 B ([256 o][64 kk] swz)
  unsigned short ytile[256][72];   // 36,864 B (o-major epilogue buffer)
};

__global__ __launch_bounds__(256) void dcn_main(
    const unsigned short* __restrict__ xT, const float* __restrict__ offs,
    const float* __restrict__ boff, const unsigned short* __restrict__ wT4,
    unsigned short* __restrict__ yb, float* __restrict__ stats) {
  __shared__ ArenaU ar;

  const int bx = blockIdx.x;
  const int lb = ((bx & 7) << 6) + (bx >> 3);   // XCD x -> image x
  const int b = lb >> 6;
  const int row = lb & 63;                      // image row
  const int pxbase = row << 6;
  const int t = threadIdx.x;
  const int lane = t & 63, wid = t >> 6;        // 4 waves
  const int obase = wid << 6;                   // wave's o-slice
  const int pl = lane & 15;                     // px within 16-px group
  const int gsub = lane >> 4;                   // granule within 32k window
  const char* xTbB = (const char*)xT + ((size_t)b << 21);

  f32x4 acc[4][4];
#pragma unroll
  for (int i = 0; i < 4; ++i)
#pragma unroll
    for (int j = 0; j < 4; ++j) {
      f32x4 z = {0.f, 0.f, 0.f, 0.f};
      acc[i][j] = z;
    }

  // per-k sampling params for the 4 px-groups this lane serves
  u32 c01[4], c23[4];
  f32x4 w4[4];
  auto cparams = [&](int k) {
    int ky = k / 3, kx = k - ky * 3;
    float by = boff[k * 2], bxo = boff[k * 2 + 1];
#pragma unroll
    for (int i = 0; i < 4; ++i) {
      int px = (i << 4) + pl;
      const float* op = offs + ((size_t)b * 4096 + pxbase + px) * 18 + k * 2;
      float py = op[0] + by + (float)(row - 1 + ky);
      float pxf = op[1] + bxo + (float)(px - 1 + kx);
      float fy = floorf(py), fx = floorf(pxf);
      float dy = py - fy, dx = pxf - fx;
      int y0 = (int)fy, x0 = (int)fx;
      int y1 = y0 + 1, x1 = x0 + 1;
      float vy0 = ((unsigned)y0 < 64u) ? 1.f : 0.f;
      float vy1 = ((unsigned)y1 < 64u) ? 1.f : 0.f;
      float vx0 = ((unsigned)x0 < 64u) ? 1.f : 0.f;
      float vx1 = ((unsigned)x1 < 64u) ? 1.f : 0.f;
      int y0c = min(max(y0, 0), 63), y1c = min(max(y1, 0), 63);
      int x0c = min(max(x0, 0), 63), x1c = min(max(x1, 0), 63);
      c01[i] = (u32)((y0c << 6) + x0c) | ((u32)((y0c << 6) + x1c) << 16);
      c23[i] = (u32)((y1c << 6) + x0c) | ((u32)((y1c << 6) + x1c) << 16);
      w4[i][0] = (1.f - dy) * (1.f - dx) * vy0 * vx0;
      w4[i][1] = (1.f - dy) * dx * vy0 * vx1;
      w4[i][2] = dy * (1.f - dx) * vy1 * vx0;
      w4[i][3] = dy * dx * vy1 * vx1;
    }
  };

  // B staging: 8KB slice per wave, async (linear dest, pre-swizzled src)
  auto stageB = [&](int tt, int d) {
    const char* src = (const char*)wT4 + ((size_t)tt << 15) + (wid << 13);
    char* dstb = (char*)&ar.Bt[d][0] + (wid << 13);
#pragma unroll
    for (int i2 = 0; i2 < 8; ++i2) {
      __builtin_amdgcn_global_load_lds(
          (const __attribute__((address_space(1))) u32*)(src + (i2 << 10) + (lane << 4)),
          (__attribute__((address_space(3))) u32*)(dstb + (i2 << 10)),
          16, 0, 0);
    }
  };

  cparams(0);
  stageB(0, 0);
  __syncthreads();

  for (int k = 0; k < 9; ++k) {
    if (k) cparams(k);
#pragma unroll
    for (int cc = 0; cc < 4; ++cc) {
      const int tt = (k << 2) + cc;
      const int d = tt & 1;
      if (tt < 35) stageB(tt + 1, d ^ 1);
#pragma unroll
      for (int s = 0; s < 2; ++s) {
        // issue 16 corner loads (4 frags x 4 corners); granule plane for this
        // lane: cc*8 + s*4 + gsub; px-group i -> contiguous 16-px addresses
        const char* base = xTbB + ((size_t)((cc << 3) + (s << 2) + gsub) << 16);
        u32x4 cr[4][4];
#pragma unroll
        for (int i = 0; i < 4; ++i) {
          cr[i][0] = *(const u32x4*)(base + ((c01[i] & 0xffffu) << 4));
          cr[i][1] = *(const u32x4*)(base + ((c01[i] >> 16) << 4));
          cr[i][2] = *(const u32x4*)(base + ((c23[i] & 0xffffu) << 4));
          cr[i][3] = *(const u32x4*)(base + ((c23[i] >> 16) << 4));
        }
        // B fragments from LDS (swizzled)
        bf16x8 bb[4];
        const int kx = (s << 6) + (gsub << 4);
#pragma unroll
        for (int j = 0; j < 4; ++j) {
          int o = obase + (j << 4) + pl;
          bb[j] = *(const bf16x8*)((const char*)&ar.Bt[d][0] + o * 128 + (kx ^ ((o & 7) << 4)));
        }
        // blend each frag into the A operand register, then 4 MFMAs
#pragma unroll
        for (int i = 0; i < 4; ++i) {
          float w0 = w4[i][0], w1 = w4[i][1], w2 = w4[i][2], w3 = w4[i][3];
          u32 o4[4];
#pragma unroll
          for (int e = 0; e < 4; ++e) {
            float lo = w0 * __uint_as_float(cr[i][0][e] << 16);
            lo = fmaf(w1, __uint_as_float(cr[i][1][e] << 16), lo);
            lo = fmaf(w2, __uint_as_float(cr[i][2][e] << 16), lo);
            lo = fmaf(w3, __uint_as_float(cr[i][3][e] << 16), lo);
            float hi = w0 * __uint_as_float(cr[i][0][e] & 0xffff0000u);
            hi = fmaf(w1, __uint_as_float(cr[i][1][e] & 0xffff0000u), hi);
            hi = fmaf(w2, __uint_as_float(cr[i][2][e] & 0xffff0000u), hi);
            hi = fmaf(w3, __uint_as_float(cr[i][3][e] & 0xffff0000u), hi);
            asm("v_cvt_pk_bf16_f32 %0, %1, %2" : "=v"(o4[e]) : "v"(lo), "v"(hi));
          }
          u32x4 av = {o4[0], o4[1], o4[2], o4[3]};
          bf16x8 af = __builtin_bit_cast(bf16x8, av);
#pragma unroll
          for (int j = 0; j < 4; ++j)
            acc[i][j] = __builtin_amdgcn_mfma_f32_16x16x32_bf16(af, bb[j], acc[i][j], 0, 0, 0);
        }
      }
      __syncthreads();
    }
  }

  // --- GroupNorm partial sums (D: col=lane&15 -> o, row=(lane>>4)*4+r -> px) ---
#pragma unroll
  for (int j = 0; j < 4; ++j) {
    float s1 = 0.f, s2 = 0.f;
#pragma unroll
    for (int i = 0; i < 4; ++i)
#pragma unroll
      for (int r = 0; r < 4; ++r) {
        float v = acc[i][j][r];
        s1 += v;
        s2 += v * v;
      }
    s1 += __shfl_xor(s1, 1, 64);  s2 += __shfl_xor(s2, 1, 64);
    s1 += __shfl_xor(s1, 2, 64);  s2 += __shfl_xor(s2, 2, 64);
    s1 += __shfl_xor(s1, 4, 64);  s2 += __shfl_xor(s2, 4, 64);
    s1 += __shfl_xor(s1, 16, 64); s2 += __shfl_xor(s2, 16, 64);
    s1 += __shfl_xor(s1, 32, 64); s2 += __shfl_xor(s2, 32, 64);
    if ((lane & 0x37) == 0) {     // lanes 0 and 8: one per 8-channel group
      int g = (obase + (j << 4) + (lane & 15)) >> 3;
      atomicAdd(&stats[((b << 5) + g) * 2 + 0], s1);
      atomicAdd(&stats[((b << 5) + g) * 2 + 1], s2);
    }
  }

  // --- acc -> ytile[o][px] bf16 (Bt arena reused; loop ended with barrier) ---
#pragma unroll
  for (int i = 0; i < 4; ++i)
#pragma unroll
    for (int j = 0; j < 4; ++j) {
      int o = obase + (j << 4) + (lane & 15);
      int pxr = (i << 4) + ((lane >> 4) << 2);
      u32 wv0, wv1;
      asm("v_cvt_pk_bf16_f32 %0, %1, %2" : "=v"(wv0) : "v"(acc[i][j][0]), "v"(acc[i][j][1]));
      asm("v_cvt_pk_bf16_f32 %0, %1, %2" : "=v"(wv1) : "v"(acc[i][j][2]), "v"(acc[i][j][3]));
      u32x2 wv = {wv0, wv1};
      *(u32x2*)((char*)ar.ytile + o * 144 + pxr * 2) = wv;
    }
  __syncthreads();
  {
    int o = t;                       // one o per thread
    const char* srcb = (const char*)ar.ytile + o * 144;
    unsigned short* dst = yb + (((size_t)(b * 256 + o)) << 12) + pxbase;
#pragma unroll
    for (int qq = 0; qq < 8; ++qq)
      *(u32x4*)((char*)dst + (qq << 4)) = *(const u32x4*)(srcb + (qq << 4));
  }
}

// ---------------------------------------------------------------------------
// K5: GroupNorm finalize + Mish — pure streaming.
// ---------------------------------------------------------------------------
__global__ __launch_bounds__(256) void gn_mish(const unsigned short* __restrict__ yb,
                                               const float* __restrict__ stats,
                                               const float* __restrict__ gamma,
                                               const float* __restrict__ beta,
                                               float* __restrict__ out) {
  int v = blockIdx.x * 512 + threadIdx.x;
#pragma unroll
  for (int it = 0; it < 2; ++it, v += 256) {
    int o = (v >> 9) & 255;
    int b = v >> 17;
    float s1 = stats[((b << 5) + (o >> 3)) * 2 + 0];
    float s2 = stats[((b << 5) + (o >> 3)) * 2 + 1];
    float mean = s1 * (1.f / 32768.f);
    float var = s2 * (1.f / 32768.f) - mean * mean;
    float rstd = rsqrtf(var + 1e-5f);
    float ga = gamma[o] * rstd, be = beta[o] - mean * gamma[o] * rstd;
    u32x4 u = *(const u32x4*)(yb + ((size_t)v << 3));
    float res[8];
#pragma unroll
    for (int e = 0; e < 4; ++e) {
      float va = __uint_as_float(u[e] << 16);
      float vb = __uint_as_float(u[e] & 0xffff0000u);
      float v0 = fmaf(va, ga, be);
      float v1 = fmaf(vb, ga, be);
      float e0 = expf(fminf(v0, 15.f));
      float e1 = expf(fminf(v1, 15.f));
      float n0 = e0 * (e0 + 2.f);
      float n1 = e1 * (e1 + 2.f);
      float m0 = v0 * (n0 / (n0 + 2.f));
      float m1 = v1 * (n1 / (n1 + 2.f));
      if (v0 > 15.f) m0 = v0;
      if (v1 > 15.f) m1 = v1;
      res[2 * e] = m0;
      res[2 * e + 1] = m1;
    }
    f32x4 o0 = {res[0], res[1], res[2], res[3]};
    f32x4 o1 = {res[4], res[5], res[6], res[7]};
    float* dst = out + ((size_t)v << 3);
    *(f32x4*)dst = o0;
    *((f32x4*)dst + 1) = o1;
  }
}

// ---------------------------------------------------------------------------
extern "C" void kernel_launch(void* const* d_in, const int* in_sizes, int n_in,
                              void* d_out, int out_size, void* d_ws, size_t ws_size,
                              hipStream_t stream) {
  const float* x     = (const float*)d_in[0];
  const float* w_off = (const float*)d_in[1];
  const float* b_off = (const float*)d_in[2];
  const float* w_dcn = (const float*)d_in[3];
  const float* gamma = (const float*)d_in[4];
  const float* beta  = (const float*)d_in[5];
  float* out = (float*)d_out;
  char* ws = (char*)d_ws;
  unsigned short* xT   = (unsigned short*)(ws);              // 16,777,216 B (bf16)
  unsigned short* yb   = (unsigned short*)(ws + 16777216);   // 16,777,216 B (bf16)
  float* offs          = (float*)(ws + 33554432);            //  2,359,296 B
  unsigned short* wT4  = (unsigned short*)(ws + 35913728);   //  1,179,648 B
  unsigned short* wOffT= (unsigned short*)(ws + 37093376);   //    147,456 B
  float* stats         = (float*)(ws + 37240832);            //      2,048 B
  prep<<<dim3(2594), dim3(256), 0, stream>>>(w_dcn, w_off, wT4, wOffT, stats);
  transpose_x<<<dim3(2048), dim3(256), 0, stream>>>(x, xT);
  conv_offset_mfma<<<dim3(256), dim3(512), 0, stream>>>(xT, wOffT, offs);
  dcn_main<<<dim3(512), dim3(256), 0, stream>>>(xT, offs, b_off, wT4, yb, stats);
  gn_mish<<<dim3(2048), dim3(256), 0, stream>>>(yb, stats, gamma, beta, out);
}

// Round 11
// 131.905 us; speedup vs baseline: 1.8936x; 1.8936x over previous
//
#include <hip/hip_runtime.h>
#include <hip/hip_bf16.h>
#include <math.h>

typedef __bf16 bf16x8 __attribute__((ext_vector_type(8)));
typedef float f32x4 __attribute__((ext_vector_type(4)));
typedef unsigned int u32;
typedef u32 u32x4 __attribute__((ext_vector_type(4)));
typedef u32 u32x2 __attribute__((ext_vector_type(2)));

// Problem constants: B=8, C=256, H=W=64, O=256, K=9, GN groups=32 (8 ch each)
// xT layout (granule-major): [b][cg=32][pix=4096][8ch] bf16; granule = 16B.

#define FENCE() __builtin_amdgcn_sched_barrier(0)
#define VMCNT(n) do { asm volatile("s_waitcnt vmcnt(" #n ")" ::: "memory"); FENCE(); } while (0)
#define LGKM0() do { asm volatile("s_waitcnt lgkmcnt(0)" ::: "memory"); FENCE(); } while (0)

__device__ inline u32 pack2bf16(float a, float b) {
  u32 ua = __float_as_uint(a);
  u32 ub = __float_as_uint(b);
  ua += 0x7fffu + ((ua >> 16) & 1u);   // RNE
  ub += 0x7fffu + ((ub >> 16) & 1u);
  return (ua >> 16) | (ub & 0xffff0000u);
}

// ---------------------------------------------------------------------------
// K0: prep — pack w_dcn into swizzled bf16 tiles, pack w_off into swizzled
// bf16 tiles (O padded 18->32), zero stats.
// ---------------------------------------------------------------------------
__global__ void prep(const float* __restrict__ w_dcn, const float* __restrict__ w_off,
                     unsigned short* __restrict__ wT4, unsigned short* __restrict__ wOffT,
                     float* __restrict__ stats) {
  size_t id = (size_t)blockIdx.x * 256 + threadIdx.x;
  if (id < 589824) {               // 256 o * 2304 ck
    int o  = (int)(id / 2304);
    int ck = (int)(id % 2304);     // ck = k*256 + c
    int k = ck >> 8, c = ck & 255;
    float v = w_dcn[(size_t)(o * 256 + c) * 9 + k];
    u32 uv = __float_as_uint(v);
    uv += 0x7fffu + ((uv >> 16) & 1u);
    int tile = ck >> 6, kk = ck & 63;
    int lin = o * 128 + kk * 2;
    int swz = lin ^ ((o & 7) << 4);
    *(unsigned short*)((char*)wT4 + (size_t)tile * 32768 + swz) = (unsigned short)(uv >> 16);
  } else if (id < 663552) {        // 36 tiles * 32 o * 64 kk = 73728
    int r = (int)(id - 589824);
    int tile = r >> 11;            // k*4 + cc
    int rr = r & 2047;
    int o = rr >> 6, kk = rr & 63;
    int k = tile >> 2, cc = tile & 3;
    int c = (cc << 6) + kk;
    float v = (o < 18) ? w_off[(size_t)(o * 256 + c) * 9 + k] : 0.f;
    u32 uv = __float_as_uint(v);
    uv += 0x7fffu + ((uv >> 16) & 1u);
    int swz = (o * 128 + kk * 2) ^ ((o & 7) << 4);
    *(unsigned short*)((char*)wOffT + (size_t)tile * 4096 + swz) = (unsigned short)(uv >> 16);
  } else if (id < 664064) {        // zero stats: 512 floats
    stats[id - 663552] = 0.f;
  }
}

// ---------------------------------------------------------------------------
// K1: transpose x [B][C][H][W] -> xT granule-major [b][cg][pix][8ch] bf16
// ---------------------------------------------------------------------------
__global__ __launch_bounds__(256) void transpose_x(const float* __restrict__ x,
                                                   unsigned short* __restrict__ xT) {
  __shared__ float tl[64][65];
  int bx = blockIdx.x;
  int b = bx >> 8;
  int y = (bx >> 2) & 63;
  int cb = (bx & 3) << 6;          // 64-ch chunk base
  int t = threadIdx.x;
  int xi = t & 63, cr = t >> 6;
  size_t base = (((size_t)(b * 256 + cb) * 64 + y) << 6);
#pragma unroll
  for (int rep = 0; rep < 16; ++rep) {
    int cl = rep * 4 + cr;
    tl[cl][xi] = x[base + (size_t)cl * 4096 + xi];
  }
  __syncthreads();
  int xw = t & 63, cpair = t >> 6;   // cpair in [0,4)
#pragma unroll
  for (int r = 0; r < 2; ++r) {
    int cgl = cpair * 2 + r;         // local granule in this 64-ch chunk
    int cg = (cb >> 3) + cgl;
    u32 pk4[4];
#pragma unroll
    for (int i = 0; i < 4; ++i)
      pk4[i] = pack2bf16(tl[cgl * 8 + 2 * i][xw], tl[cgl * 8 + 2 * i + 1][xw]);
    u32x4 v = {pk4[0], pk4[1], pk4[2], pk4[3]};
    *(u32x4*)((char*)xT + (((size_t)b << 21)) + ((size_t)cg << 16) + ((y << 6) + xw) * 16) = v;
  }
}

// ---------------------------------------------------------------------------
// K2: offset conv via MFMA (unchanged from R9).
// ---------------------------------------------------------------------------
__global__ __launch_bounds__(512, 2) void conv_offset_mfma(
    const unsigned short* __restrict__ xT, const unsigned short* __restrict__ wOffT,
    float* __restrict__ offs) {
  __shared__ unsigned short A[2][128][64]; // 32KB, byte ^= (row&7)<<4
  __shared__ unsigned short Bo[2][2048];   // 8KB  ([32 o][64 kk], swizzled)
  const int bx = blockIdx.x;
  const int lb = ((bx & 7) << 5) + (bx >> 3);   // XCD x -> image x
  const int b = lb >> 5;
  const int rp = lb & 31;          // row pair
  const int t = threadIdx.x;
  const int lane = t & 63, wid = t >> 6;   // wid 0..7
  const char* xTbB = (const char*)xT + ((size_t)b << 21);
  const int p = t >> 2;            // local pixel 0..127
  const int row = (rp << 1) + (p >> 6);
  const int xx = p & 63;
  const int cpl = (t & 3) << 1;    // granule-pair slot within cc-chunk

  f32x4 acc[2];
  {
    f32x4 z = {0.f, 0.f, 0.f, 0.f};
    acc[0] = z; acc[1] = z;
  }

  u32x4 ra = {0u,0u,0u,0u}, rb = {0u,0u,0u,0u};

  auto issue = [&](int tt, int d) {
    int k = tt >> 2, cc = tt & 3;
    int ky = k / 3, kx = k - ky * 3;
    int ys = row - 1 + ky;
    int xs = xx - 1 + kx;
    bool ok = ((unsigned)ys < 64u) && ((unsigned)xs < 64u);
    u32x4 z = {0u,0u,0u,0u};
    ra = z; rb = z;
    if (ok) {
      const char* s0 = xTbB + ((size_t)(cc * 8 + cpl) << 16) + (((ys << 6) + xs) << 4);
      ra = *(const u32x4*)s0;
      rb = *(const u32x4*)(s0 + 65536);
    }
    if (wid < 4)
      __builtin_amdgcn_global_load_lds(
          (const __attribute__((address_space(1))) u32*)((const char*)wOffT + ((size_t)tt << 12) + (wid << 10) + (lane << 4)),
          (__attribute__((address_space(3))) u32*)((char*)&Bo[d][0] + (wid << 10)),
          16, 0, 0);
  };
  auto writeA = [&](int d) {
    char* dst = (char*)&A[d][0][0] + p * 128;
    int b0 = (t & 3) << 5;
    int sw = (p & 7) << 4;
    *(u32x4*)(dst + (b0 ^ sw)) = ra;
    *(u32x4*)(dst + ((b0 + 16) ^ sw)) = rb;
  };

  issue(0, 0);
  writeA(0);
  __syncthreads();

  int cur = 0;
  for (int tt = 0; tt < 36; ++tt) {
    if (tt < 35) issue(tt + 1, cur ^ 1);
#pragma unroll
    for (int s = 0; s < 2; ++s) {
      int r16 = (wid << 4) + (lane & 15);
      int kx = (s << 6) + ((lane >> 4) << 4);
      bf16x8 a = *(const bf16x8*)((const char*)&A[cur][0][0] + r16 * 128 + (kx ^ ((r16 & 7) << 4)));
#pragma unroll
      for (int j = 0; j < 2; ++j) {
        int o = (j << 4) + (lane & 15);
        bf16x8 bv = *(const bf16x8*)((const char*)&Bo[cur][0] + o * 128 + (kx ^ ((o & 7) << 4)));
        acc[j] = __builtin_amdgcn_mfma_f32_16x16x32_bf16(a, bv, acc[j], 0, 0, 0);
      }
    }
    if (tt < 35) writeA(cur ^ 1);
    __syncthreads();
    cur ^= 1;
  }

#pragma unroll
  for (int j = 0; j < 2; ++j) {
    int o = (j << 4) + (lane & 15);
    if (o < 18) {
#pragma unroll
      for (int r = 0; r < 4; ++r) {
        int pl = (wid << 4) + ((lane >> 4) << 2) + r;
        offs[((size_t)b * 4096 + (rp << 7) + pl) * 18 + o] = acc[j][r];
      }
    }
  }
}

// ---------------------------------------------------------------------------
// K4: main fused kernel — COUNTED-VMCNT PIPELINE (T3/T4), single raw barrier
// per step, never vmcnt(0) in the loop.
// block = 128 px x 256 O, 512 thr, 8 waves (wave = 64px x 64o, acc[4][4]).
// Staging: thread = px((wid&1)*64+lane) x 2 granules ((wid>>1)*2).
// Loop VMEM per wave per step: 8 A-corner loads + 4 B gload_lds = 12.
// FIFO discipline: mid-body vmcnt(4) -> A(t+1) done; end-of-body vmcnt(12)
// -> own B(t+1) landed BEFORE barrier (cross-wave safe). B tri-buffered so
// the 2-ahead gload never lands in a buffer another wave may still read.
// ---------------------------------------------------------------------------
union ArenaM {
  struct {
    unsigned short A[2][128][64];   //  32,768 B (byte ^= (row&7)<<4)
    unsigned short Bt[3][16384];    //  98,304 B ([256 o][64 kk] swz)
  } m;
  unsigned short ytile[256][136];   //  69,632 B (o-major epilogue buffer)
};

__global__ __launch_bounds__(512) void dcn_main(
    const unsigned short* __restrict__ xT, const float* __restrict__ offs,
    const float* __restrict__ boff, const unsigned short* __restrict__ wT4,
    unsigned short* __restrict__ yb, float* __restrict__ stats) {
  __shared__ ArenaM ar;
  __shared__ u32 pcor[9][128][2];   //  9,216 B (c01, c23 per (k,px))
  __shared__ float pwt[9][128][4];  // 18,432 B (4 bilinear weights)

  const int bx = blockIdx.x;
  const int lb = ((bx & 7) << 5) + (bx >> 3);   // XCD x -> image x
  const int b = lb >> 5;
  const int pxbase = (lb & 31) << 7;            // 128-px group (2 rows)
  const int t = threadIdx.x;
  const int lane = t & 63, wid = t >> 6;        // wid 0..7
  const char* xTbB = (const char*)xT + ((size_t)b << 21);
  // staging: px consecutive per wave -> coalesced corner loads
  const int pxs = ((wid & 1) << 6) + lane;
  const int gp = (wid >> 1) << 1;               // granules gp, gp+1
  // mfma: wave (wr px-half) x (wc o-slice)
  const int wr = wid >> 2, wc = wid & 3;
  const int obase = wc << 6;

  // --- prologue: per-(k,px) sampling params into LDS ---
  for (int idx = t; idx < 1152; idx += 512) {
    int k = idx >> 7, px = idx & 127;
    int pxg = pxbase + px;
    int yy = pxg >> 6, xx = pxg & 63;
    int ky = k / 3, kx = k - ky * 3;
    const float* op = offs + ((size_t)b * 4096 + pxg) * 18 + k * 2;
    float py = op[0] + boff[k * 2] + (float)(yy - 1 + ky);
    float pxf = op[1] + boff[k * 2 + 1] + (float)(xx - 1 + kx);
    float fy = floorf(py), fx = floorf(pxf);
    float dy = py - fy, dx = pxf - fx;
    int y0 = (int)fy, x0 = (int)fx;
    int y1 = y0 + 1, x1 = x0 + 1;
    float vy0 = ((unsigned)y0 < 64u) ? 1.f : 0.f;
    float vy1 = ((unsigned)y1 < 64u) ? 1.f : 0.f;
    float vx0 = ((unsigned)x0 < 64u) ? 1.f : 0.f;
    float vx1 = ((unsigned)x1 < 64u) ? 1.f : 0.f;
    int y0c = min(max(y0, 0), 63), y1c = min(max(y1, 0), 63);
    int x0c = min(max(x0, 0), 63), x1c = min(max(x1, 0), 63);
    pcor[k][px][0] = (u32)((y0c << 6) + x0c) | ((u32)((y0c << 6) + x1c) << 16);
    pcor[k][px][1] = (u32)((y1c << 6) + x0c) | ((u32)((y1c << 6) + x1c) << 16);
    pwt[k][px][0] = (1.f - dy) * (1.f - dx) * vy0 * vx0;
    pwt[k][px][1] = (1.f - dy) * dx * vy0 * vx1;
    pwt[k][px][2] = dy * (1.f - dx) * vy1 * vx0;
    pwt[k][px][3] = dy * dx * vy1 * vx1;
  }

  f32x4 acc[4][4];
#pragma unroll
  for (int i = 0; i < 4; ++i)
#pragma unroll
    for (int j = 0; j < 4; ++j) {
      f32x4 z = {0.f, 0.f, 0.f, 0.f};
      acc[i][j] = z;
    }

  __syncthreads();                 // params ready (one full drain, prologue only)

  u32x4 rA[8];                     // in-flight corners: 2 granules x 4 corners

  auto issueA = [&](int tt) {      // 8 VMEM loads, coalesced (px = lane-consec)
    int k = tt >> 2, cc = tt & 3;
    u32 c01 = pcor[k][pxs][0], c23 = pcor[k][pxs][1];
    const char* p0 = xTbB + ((size_t)((cc << 3) + gp) << 16);
#pragma unroll
    for (int g = 0; g < 2; ++g) {
      const char* bgp = p0 + ((size_t)g << 16);
      rA[g * 4 + 0] = *(const u32x4*)(bgp + ((size_t)(c01 & 0xffffu) << 4));
      rA[g * 4 + 1] = *(const u32x4*)(bgp + ((size_t)(c01 >> 16) << 4));
      rA[g * 4 + 2] = *(const u32x4*)(bgp + ((size_t)(c23 & 0xffffu) << 4));
      rA[g * 4 + 3] = *(const u32x4*)(bgp + ((size_t)(c23 >> 16) << 4));
    }
  };
  auto issueB = [&](int tt, int bufi) {   // 4 gload_lds, 4KB slice per wave
    const char* src = (const char*)wT4 + ((size_t)tt << 15) + (wid << 12);
    char* dstb = (char*)&ar.m.Bt[bufi][0] + (wid << 12);
#pragma unroll
    for (int i2 = 0; i2 < 4; ++i2) {
      __builtin_amdgcn_global_load_lds(
          (const __attribute__((address_space(1))) u32*)(src + (i2 << 10) + (lane << 4)),
          (__attribute__((address_space(3))) u32*)(dstb + (i2 << 10)),
          16, 0, 0);
    }
  };
  auto blendA = [&](int tt) {      // blend rA -> bf16, swizzled ds_write
    int k = tt >> 2;
    f32x4 w = *(const f32x4*)&pwt[k][pxs][0];
    char* dst = (char*)&ar.m.A[tt & 1][0][0] + pxs * 128;
    int sw = (pxs & 7) << 4;
#pragma unroll
    for (int g = 0; g < 2; ++g) {
      u32 o4[4];
#pragma unroll
      for (int e = 0; e < 4; ++e) {
        u32 u0 = rA[g * 4 + 0][e], u1 = rA[g * 4 + 1][e];
        u32 u2 = rA[g * 4 + 2][e], u3 = rA[g * 4 + 3][e];
        float lo = w[0] * __uint_as_float(u0 << 16);
        lo = fmaf(w[1], __uint_as_float(u1 << 16), lo);
        lo = fmaf(w[2], __uint_as_float(u2 << 16), lo);
        lo = fmaf(w[3], __uint_as_float(u3 << 16), lo);
        float hi = w[0] * __uint_as_float(u0 & 0xffff0000u);
        hi = fmaf(w[1], __uint_as_float(u1 & 0xffff0000u), hi);
        hi = fmaf(w[2], __uint_as_float(u2 & 0xffff0000u), hi);
        hi = fmaf(w[3], __uint_as_float(u3 & 0xffff0000u), hi);
        asm("v_cvt_pk_bf16_f32 %0, %1, %2" : "=v"(o4[e]) : "v"(lo), "v"(hi));
      }
      u32x4 ov = {o4[0], o4[1], o4[2], o4[3]};
      *(u32x4*)(dst + (((gp + g) << 4) ^ sw)) = ov;
    }
  };

  // --- pipeline prologue ---
  issueA(0); FENCE();
  issueB(0, 0); FENCE();
  VMCNT(4);                        // A(0) done (B(0) may fly)
  blendA(0);
  FENCE();
  issueA(1); FENCE();
  issueB(1, 1); FENCE();
  VMCNT(12);                       // own B(0) landed
  LGKM0();
  __builtin_amdgcn_s_barrier();

  int bm3 = 0;                     // tt % 3
  for (int tt = 0; tt < 36; ++tt) {
    // --- MFMA(tt) ---
    {
      const char* Ab = (const char*)&ar.m.A[tt & 1][0][0];
      const char* Bb = (const char*)&ar.m.Bt[bm3][0];
      __builtin_amdgcn_s_setprio(1);
#pragma unroll
      for (int s = 0; s < 2; ++s) {
        int kx = (s << 6) + ((lane >> 4) << 4);
        bf16x8 a[4], bb[4];
#pragma unroll
        for (int i = 0; i < 4; ++i) {
          int r16 = (wr << 6) + (i << 4) + (lane & 15);
          a[i] = *(const bf16x8*)(Ab + r16 * 128 + (kx ^ ((r16 & 7) << 4)));
        }
#pragma unroll
        for (int j = 0; j < 4; ++j) {
          int o = obase + (j << 4) + (lane & 15);
          bb[j] = *(const bf16x8*)(Bb + o * 128 + (kx ^ ((o & 7) << 4)));
        }
#pragma unroll
        for (int i = 0; i < 4; ++i)
#pragma unroll
          for (int j = 0; j < 4; ++j)
            acc[i][j] = __builtin_amdgcn_mfma_f32_16x16x32_bf16(a[i], bb[j], acc[i][j], 0, 0, 0);
      }
      __builtin_amdgcn_s_setprio(0);
    }
    FENCE();
    if (tt < 35) {
      VMCNT(4);                    // A(tt+1) corners done (B(tt+1) may fly)
      blendA(tt + 1);
      FENCE();
      if (tt < 34) {
        issueA(tt + 2); FENCE();
        int bn = bm3 + 2; if (bn >= 3) bn -= 3;
        issueB(tt + 2, bn); FENCE();
      }
    }
    if (tt == 34) { VMCNT(0); }    // force B(35) before last barrier
    else { VMCNT(12); }            // own B(tt+1) landed; keep t+2 in flight
    LGKM0();
    __builtin_amdgcn_s_barrier();
    FENCE();
    bm3 = (bm3 == 2) ? 0 : bm3 + 1;
  }

  // --- GroupNorm partial sums (D: col=lane&15 -> o, row=(lane>>4)*4+r -> px) ---
#pragma unroll
  for (int j = 0; j < 4; ++j) {
    float s1 = 0.f, s2 = 0.f;
#pragma unroll
    for (int i = 0; i < 4; ++i)
#pragma unroll
      for (int r = 0; r < 4; ++r) {
        float v = acc[i][j][r];
        s1 += v;
        s2 += v * v;
      }
    s1 += __shfl_xor(s1, 1, 64);  s2 += __shfl_xor(s2, 1, 64);
    s1 += __shfl_xor(s1, 2, 64);  s2 += __shfl_xor(s2, 2, 64);
    s1 += __shfl_xor(s1, 4, 64);  s2 += __shfl_xor(s2, 4, 64);
    s1 += __shfl_xor(s1, 16, 64); s2 += __shfl_xor(s2, 16, 64);
    s1 += __shfl_xor(s1, 32, 64); s2 += __shfl_xor(s2, 32, 64);
    if ((lane & 0x37) == 0) {     // lanes 0 and 8: one per 8-channel group
      int g = (obase + (j << 4) + (lane & 15)) >> 3;
      atomicAdd(&stats[((b << 5) + g) * 2 + 0], s1);
      atomicAdd(&stats[((b << 5) + g) * 2 + 1], s2);
    }
  }

  // --- acc -> ytile[o][px] bf16 -> yb[b][o][px] (final barrier crossed) ---
#pragma unroll
  for (int i = 0; i < 4; ++i)
#pragma unroll
    for (int j = 0; j < 4; ++j) {
      int o = obase + (j << 4) + (lane & 15);
      int pxr = (wr << 6) + (i << 4) + ((lane >> 4) << 2);
      u32 wv0, wv1;
      asm("v_cvt_pk_bf16_f32 %0, %1, %2" : "=v"(wv0) : "v"(acc[i][j][0]), "v"(acc[i][j][1]));
      asm("v_cvt_pk_bf16_f32 %0, %1, %2" : "=v"(wv1) : "v"(acc[i][j][2]), "v"(acc[i][j][3]));
      u32x2 wv = {wv0, wv1};
      *(u32x2*)((char*)ar.ytile + o * 272 + pxr * 2) = wv;
    }
  __syncthreads();
  {
    int o = t >> 1, half = t & 1;
    const char* srcb = (const char*)ar.ytile + o * 272 + (half << 7);
    unsigned short* dst = yb + (((size_t)(b * 256 + o)) << 12) + pxbase + (half << 6);
#pragma unroll
    for (int qq = 0; qq < 8; ++qq)
      *(u32x4*)((char*)dst + (qq << 4)) = *(const u32x4*)(srcb + (qq << 4));
  }
}

// ---------------------------------------------------------------------------
// K5: GroupNorm finalize + Mish — pure streaming.
// ---------------------------------------------------------------------------
__global__ __launch_bounds__(256) void gn_mish(const unsigned short* __restrict__ yb,
                                               const float* __restrict__ stats,
                                               const float* __restrict__ gamma,
                                               const float* __restrict__ beta,
                                               float* __restrict__ out) {
  int v = blockIdx.x * 512 + threadIdx.x;
#pragma unroll
  for (int it = 0; it < 2; ++it, v += 256) {
    int o = (v >> 9) & 255;
    int b = v >> 17;
    float s1 = stats[((b << 5) + (o >> 3)) * 2 + 0];
    float s2 = stats[((b << 5) + (o >> 3)) * 2 + 1];
    float mean = s1 * (1.f / 32768.f);
    float var = s2 * (1.f / 32768.f) - mean * mean;
    float rstd = rsqrtf(var + 1e-5f);
    float ga = gamma[o] * rstd, be = beta[o] - mean * gamma[o] * rstd;
    u32x4 u = *(const u32x4*)(yb + ((size_t)v << 3));
    float res[8];
#pragma unroll
    for (int e = 0; e < 4; ++e) {
      float va = __uint_as_float(u[e] << 16);
      float vb = __uint_as_float(u[e] & 0xffff0000u);
      float v0 = fmaf(va, ga, be);
      float v1 = fmaf(vb, ga, be);
      float e0 = expf(fminf(v0, 15.f));
      float e1 = expf(fminf(v1, 15.f));
      float n0 = e0 * (e0 + 2.f);
      float n1 = e1 * (e1 + 2.f);
      float m0 = v0 * (n0 / (n0 + 2.f));
      float m1 = v1 * (n1 / (n1 + 2.f));
      if (v0 > 15.f) m0 = v0;
      if (v1 > 15.f) m1 = v1;
      res[2 * e] = m0;
      res[2 * e + 1] = m1;
    }
    f32x4 o0 = {res[0], res[1], res[2], res[3]};
    f32x4 o1 = {res[4], res[5], res[6], res[7]};
    float* dst = out + ((size_t)v << 3);
    *(f32x4*)dst = o0;
    *((f32x4*)dst + 1) = o1;
  }
}

// ---------------------------------------------------------------------------
extern "C" void kernel_launch(void* const* d_in, const int* in_sizes, int n_in,
                              void* d_out, int out_size, void* d_ws, size_t ws_size,
                              hipStream_t stream) {
  const float* x     = (const float*)d_in[0];
  const float* w_off = (const float*)d_in[1];
  const float* b_off = (const float*)d_in[2];
  const float* w_dcn = (const float*)d_in[3];
  const float* gamma = (const float*)d_in[4];
  const float* beta  = (const float*)d_in[5];
  float* out = (float*)d_out;
  char* ws = (char*)d_ws;
  unsigned short* xT   = (unsigned short*)(ws);              // 16,777,216 B (bf16)
  unsigned short* yb   = (unsigned short*)(ws + 16777216);   // 16,777,216 B (bf16)
  float* offs          = (float*)(ws + 33554432);            //  2,359,296 B
  unsigned short* wT4  = (unsigned short*)(ws + 35913728);   //  1,179,648 B
  unsigned short* wOffT= (unsigned short*)(ws + 37093376);   //    147,456 B
  float* stats         = (float*)(ws + 37240832);            //      2,048 B
  prep<<<dim3(2594), dim3(256), 0, stream>>>(w_dcn, w_off, wT4, wOffT, stats);
  transpose_x<<<dim3(2048), dim3(256), 0, stream>>>(x, xT);
  conv_offset_mfma<<<dim3(256), dim3(512), 0, stream>>>(xT, wOffT, offs);
  dcn_main<<<dim3(256), dim3(512), 0, stream>>>(xT, offs, b_off, wT4, yb, stats);
  gn_mish<<<dim3(2048), dim3(256), 0, stream>>>(yb, stats, gamma, beta, out);
}

// Round 12
// 125.749 us; speedup vs baseline: 1.9863x; 1.0490x over previous
//
#include <hip/hip_runtime.h>
#include <hip/hip_bf16.h>
#include <math.h>

typedef __bf16 bf16x8 __attribute__((ext_vector_type(8)));
typedef float f32x4 __attribute__((ext_vector_type(4)));
typedef float f32x2 __attribute__((ext_vector_type(2)));
typedef unsigned int u32;
typedef u32 u32x4 __attribute__((ext_vector_type(4)));
typedef u32 u32x2 __attribute__((ext_vector_type(2)));

// Problem constants: B=8, C=256, H=W=64, O=256, K=9, GN groups=32 (8 ch each)
// xT layout (granule-major): [b][cg=32][pix=4096][8ch] bf16; granule = 16B.

#define FENCE() __builtin_amdgcn_sched_barrier(0)
#define VMCNT(n) do { asm volatile("s_waitcnt vmcnt(" #n ")" ::: "memory"); FENCE(); } while (0)
#define LGKM0() do { asm volatile("s_waitcnt lgkmcnt(0)" ::: "memory"); FENCE(); } while (0)

__device__ inline u32 pack2bf16(float a, float b) {
  u32 ua = __float_as_uint(a);
  u32 ub = __float_as_uint(b);
  ua += 0x7fffu + ((ua >> 16) & 1u);   // RNE
  ub += 0x7fffu + ((ub >> 16) & 1u);
  return (ua >> 16) | (ub & 0xffff0000u);
}

// ---------------------------------------------------------------------------
// K0: prep — pack w_dcn into swizzled bf16 tiles, pack w_off into swizzled
// bf16 tiles (O padded 18->32), zero stats.
// ---------------------------------------------------------------------------
__global__ void prep(const float* __restrict__ w_dcn, const float* __restrict__ w_off,
                     unsigned short* __restrict__ wT4, unsigned short* __restrict__ wOffT,
                     float* __restrict__ stats) {
  size_t id = (size_t)blockIdx.x * 256 + threadIdx.x;
  if (id < 589824) {               // 256 o * 2304 ck
    int o  = (int)(id / 2304);
    int ck = (int)(id % 2304);     // ck = k*256 + c
    int k = ck >> 8, c = ck & 255;
    float v = w_dcn[(size_t)(o * 256 + c) * 9 + k];
    u32 uv = __float_as_uint(v);
    uv += 0x7fffu + ((uv >> 16) & 1u);
    int tile = ck >> 6, kk = ck & 63;
    int lin = o * 128 + kk * 2;
    int swz = lin ^ ((o & 7) << 4);
    *(unsigned short*)((char*)wT4 + (size_t)tile * 32768 + swz) = (unsigned short)(uv >> 16);
  } else if (id < 663552) {        // 36 tiles * 32 o * 64 kk = 73728
    int r = (int)(id - 589824);
    int tile = r >> 11;            // k*4 + cc
    int rr = r & 2047;
    int o = rr >> 6, kk = rr & 63;
    int k = tile >> 2, cc = tile & 3;
    int c = (cc << 6) + kk;
    float v = (o < 18) ? w_off[(size_t)(o * 256 + c) * 9 + k] : 0.f;
    u32 uv = __float_as_uint(v);
    uv += 0x7fffu + ((uv >> 16) & 1u);
    int swz = (o * 128 + kk * 2) ^ ((o & 7) << 4);
    *(unsigned short*)((char*)wOffT + (size_t)tile * 4096 + swz) = (unsigned short)(uv >> 16);
  } else if (id < 664064) {        // zero stats: 512 floats
    stats[id - 663552] = 0.f;
  }
}

// ---------------------------------------------------------------------------
// K1: transpose x [B][C][H][W] -> xT granule-major [b][cg][pix][8ch] bf16
// ---------------------------------------------------------------------------
__global__ __launch_bounds__(256) void transpose_x(const float* __restrict__ x,
                                                   unsigned short* __restrict__ xT) {
  __shared__ float tl[64][65];
  int bx = blockIdx.x;
  int b = bx >> 8;
  int y = (bx >> 2) & 63;
  int cb = (bx & 3) << 6;          // 64-ch chunk base
  int t = threadIdx.x;
  int xi = t & 63, cr = t >> 6;
  size_t base = (((size_t)(b * 256 + cb) * 64 + y) << 6);
#pragma unroll
  for (int rep = 0; rep < 16; ++rep) {
    int cl = rep * 4 + cr;
    tl[cl][xi] = x[base + (size_t)cl * 4096 + xi];
  }
  __syncthreads();
  int xw = t & 63, cpair = t >> 6;   // cpair in [0,4)
#pragma unroll
  for (int r = 0; r < 2; ++r) {
    int cgl = cpair * 2 + r;         // local granule in this 64-ch chunk
    int cg = (cb >> 3) + cgl;
    u32 pk4[4];
#pragma unroll
    for (int i = 0; i < 4; ++i)
      pk4[i] = pack2bf16(tl[cgl * 8 + 2 * i][xw], tl[cgl * 8 + 2 * i + 1][xw]);
    u32x4 v = {pk4[0], pk4[1], pk4[2], pk4[3]};
    *(u32x4*)((char*)xT + (((size_t)b << 21)) + ((size_t)cg << 16) + ((y << 6) + xw) * 16) = v;
  }
}

// ---------------------------------------------------------------------------
// K2: offset conv — DIRECT-A GEMM. A-frags (integer taps) load straight from
// granule-major xT into MFMA registers (lane = px(l&15) x granule(l>>4) ==
// frag layout). 4 independent waves (wave = 64-ch chunk), per-wave B dbuf via
// gload_lds + counted vmcnt, ZERO barriers in the K-loop. Epilogue: LDS
// cross-wave reduce (union with Bo) -> offs.
// grid 512 = 8 img x 64 rows, 256 thr.
// ---------------------------------------------------------------------------
__global__ __launch_bounds__(256) void conv_offset_mfma(
    const unsigned short* __restrict__ xT, const unsigned short* __restrict__ wOffT,
    float* __restrict__ offs) {
  __shared__ union {
    unsigned short Bo[4][2][2048];   // [wave][dbuf][32o x 64kk] = 32 KB
    float red[4][64][32];            // [wave][px][o] partials   = 32 KB
  } sm;
  const int bx = blockIdx.x;
  const int lb = ((bx & 7) << 6) + (bx >> 3);   // XCD x -> image x
  const int b = lb >> 6;
  const int row = lb & 63;
  const int t = threadIdx.x;
  const int lane = t & 63, w = t >> 6;          // 4 waves, wave = c-chunk w
  const char* xTbB = (const char*)xT + ((size_t)b << 21);

  f32x4 acc[4][2];
#pragma unroll
  for (int i = 0; i < 4; ++i)
#pragma unroll
    for (int j = 0; j < 2; ++j) {
      f32x4 z = {0.f, 0.f, 0.f, 0.f};
      acc[i][j] = z;
    }

  auto stageB = [&](int k, int d) {   // tile (k*4 + w), 4 KB, own LDS slice
    const char* src = (const char*)wOffT + ((size_t)((k << 2) + w) << 12);
    char* dstb = (char*)&sm.Bo[w][d][0];
#pragma unroll
    for (int i2 = 0; i2 < 4; ++i2) {
      __builtin_amdgcn_global_load_lds(
          (const __attribute__((address_space(1))) u32*)(src + (i2 << 10) + (lane << 4)),
          (__attribute__((address_space(3))) u32*)(dstb + (i2 << 10)),
          16, 0, 0);
    }
  };

  stageB(0, 0);
  u32x4 rA[8];
  const u32x4 zv = {0u, 0u, 0u, 0u};

  for (int k = 0; k < 9; ++k) {
    int ky = k / 3, kxv = k - ky * 3;
    int rowp = row - 1 + ky;
    bool rok = ((unsigned)rowp < 64u);   // block-uniform
    bool ok[4];
    if (rok) {
      int pix[4];
#pragma unroll
      for (int pg = 0; pg < 4; ++pg) {
        int xs = (pg << 4) + (lane & 15) + kxv - 1;
        ok[pg] = ((unsigned)xs < 64u);
        int xc = min(max(xs, 0), 63);
        pix[pg] = (rowp << 6) + xc;
      }
#pragma unroll
      for (int s = 0; s < 2; ++s) {
        const char* base = xTbB + ((size_t)((w << 3) + (s << 2) + (lane >> 4)) << 16);
#pragma unroll
        for (int pg = 0; pg < 4; ++pg)
          rA[s * 4 + pg] = *(const u32x4*)(base + ((size_t)pix[pg] << 4));
      }
    }
    if (k < 8) stageB(k + 1, (k + 1) & 1);
    VMCNT(4);                            // A(k) + B(k) done; B(k+1) in flight
    if (rok) {
      const char* Bb = (const char*)&sm.Bo[w][k & 1][0];
#pragma unroll
      for (int s = 0; s < 2; ++s) {
        bf16x8 bb[2];
        int kx = (s << 6) + ((lane >> 4) << 4);
#pragma unroll
        for (int j = 0; j < 2; ++j) {
          int o = (j << 4) + (lane & 15);
          bb[j] = *(const bf16x8*)(Bb + o * 128 + (kx ^ ((o & 7) << 4)));
        }
#pragma unroll
        for (int pg = 0; pg < 4; ++pg) {
          u32x4 av = ok[pg] ? rA[s * 4 + pg] : zv;
          bf16x8 af = __builtin_bit_cast(bf16x8, av);
#pragma unroll
          for (int j = 0; j < 2; ++j)
            acc[pg][j] = __builtin_amdgcn_mfma_f32_16x16x32_bf16(af, bb[j], acc[pg][j], 0, 0, 0);
        }
      }
    }
  }

  // epilogue: partials into own LDS slice (aliases own Bo), reduce, write offs
#pragma unroll
  for (int pg = 0; pg < 4; ++pg)
#pragma unroll
    for (int j = 0; j < 2; ++j)
#pragma unroll
      for (int r = 0; r < 4; ++r) {
        int px = (pg << 4) + ((lane >> 4) << 2) + r;
        int o = (j << 4) + (lane & 15);
        sm.red[w][px][o] = acc[pg][j][r];
      }
  __syncthreads();
  {
    int px = t >> 2, oq = (t & 3) << 3;
#pragma unroll
    for (int e = 0; e < 8; ++e) {
      int o = oq + e;
      if (o < 18) {
        float sv = sm.red[0][px][o] + sm.red[1][px][o]
                 + sm.red[2][px][o] + sm.red[3][px][o];
        offs[((size_t)b * 4096 + (row << 6) + px) * 18 + o] = sv;
      }
    }
  }
}

// ---------------------------------------------------------------------------
// K4: main fused kernel — counted-vmcnt pipeline; blend moved BEFORE the MFMA
// cluster (ds_write latency hides under MFMA; barrier tail = drained vmcnt);
// blend vectorized to f32x2 (v_pk_fma_f32).
// block = 128 px x 256 O, 512 thr, 8 waves (wave = 64px x 64o, acc[4][4]).
// ---------------------------------------------------------------------------
union ArenaM {
  struct {
    unsigned short A[2][128][64];   //  32,768 B (byte ^= (row&7)<<4)
    unsigned short Bt[3][16384];    //  98,304 B ([256 o][64 kk] swz)
  } m;
  unsigned short ytile[256][136];   //  69,632 B (o-major epilogue buffer)
};

__global__ __launch_bounds__(512) void dcn_main(
    const unsigned short* __restrict__ xT, const float* __restrict__ offs,
    const float* __restrict__ boff, const unsigned short* __restrict__ wT4,
    unsigned short* __restrict__ yb, float* __restrict__ stats) {
  __shared__ ArenaM ar;
  __shared__ u32 pcor[9][128][2];   //  9,216 B (c01, c23 per (k,px))
  __shared__ float pwt[9][128][4];  // 18,432 B (4 bilinear weights)

  const int bx = blockIdx.x;
  const int lb = ((bx & 7) << 5) + (bx >> 3);   // XCD x -> image x
  const int b = lb >> 5;
  const int pxbase = (lb & 31) << 7;            // 128-px group (2 rows)
  const int t = threadIdx.x;
  const int lane = t & 63, wid = t >> 6;        // wid 0..7
  const char* xTbB = (const char*)xT + ((size_t)b << 21);
  const int pxs = ((wid & 1) << 6) + lane;      // staging px (lane-consec)
  const int gp = (wid >> 1) << 1;               // granules gp, gp+1
  const int wr = wid >> 2, wc = wid & 3;
  const int obase = wc << 6;

  // --- prologue: per-(k,px) sampling params into LDS ---
  for (int idx = t; idx < 1152; idx += 512) {
    int k = idx >> 7, px = idx & 127;
    int pxg = pxbase + px;
    int yy = pxg >> 6, xx = pxg & 63;
    int ky = k / 3, kx = k - ky * 3;
    const float* op = offs + ((size_t)b * 4096 + pxg) * 18 + k * 2;
    float py = op[0] + boff[k * 2] + (float)(yy - 1 + ky);
    float pxf = op[1] + boff[k * 2 + 1] + (float)(xx - 1 + kx);
    float fy = floorf(py), fx = floorf(pxf);
    float dy = py - fy, dx = pxf - fx;
    int y0 = (int)fy, x0 = (int)fx;
    int y1 = y0 + 1, x1 = x0 + 1;
    float vy0 = ((unsigned)y0 < 64u) ? 1.f : 0.f;
    float vy1 = ((unsigned)y1 < 64u) ? 1.f : 0.f;
    float vx0 = ((unsigned)x0 < 64u) ? 1.f : 0.f;
    float vx1 = ((unsigned)x1 < 64u) ? 1.f : 0.f;
    int y0c = min(max(y0, 0), 63), y1c = min(max(y1, 0), 63);
    int x0c = min(max(x0, 0), 63), x1c = min(max(x1, 0), 63);
    pcor[k][px][0] = (u32)((y0c << 6) + x0c) | ((u32)((y0c << 6) + x1c) << 16);
    pcor[k][px][1] = (u32)((y1c << 6) + x0c) | ((u32)((y1c << 6) + x1c) << 16);
    pwt[k][px][0] = (1.f - dy) * (1.f - dx) * vy0 * vx0;
    pwt[k][px][1] = (1.f - dy) * dx * vy0 * vx1;
    pwt[k][px][2] = dy * (1.f - dx) * vy1 * vx0;
    pwt[k][px][3] = dy * dx * vy1 * vx1;
  }

  f32x4 acc[4][4];
#pragma unroll
  for (int i = 0; i < 4; ++i)
#pragma unroll
    for (int j = 0; j < 4; ++j) {
      f32x4 z = {0.f, 0.f, 0.f, 0.f};
      acc[i][j] = z;
    }

  __syncthreads();                 // params ready

  u32x4 rA[8];                     // in-flight corners: 2 granules x 4 corners

  auto issueA = [&](int tt) {      // 8 VMEM loads, coalesced
    int k = tt >> 2, cc = tt & 3;
    u32 c01 = pcor[k][pxs][0], c23 = pcor[k][pxs][1];
    const char* p0 = xTbB + ((size_t)((cc << 3) + gp) << 16);
#pragma unroll
    for (int g = 0; g < 2; ++g) {
      const char* bgp = p0 + ((size_t)g << 16);
      rA[g * 4 + 0] = *(const u32x4*)(bgp + ((size_t)(c01 & 0xffffu) << 4));
      rA[g * 4 + 1] = *(const u32x4*)(bgp + ((size_t)(c01 >> 16) << 4));
      rA[g * 4 + 2] = *(const u32x4*)(bgp + ((size_t)(c23 & 0xffffu) << 4));
      rA[g * 4 + 3] = *(const u32x4*)(bgp + ((size_t)(c23 >> 16) << 4));
    }
  };
  auto issueB = [&](int tt, int bufi) {   // 4 gload_lds, 4KB slice per wave
    const char* src = (const char*)wT4 + ((size_t)tt << 15) + (wid << 12);
    char* dstb = (char*)&ar.m.Bt[bufi][0] + (wid << 12);
#pragma unroll
    for (int i2 = 0; i2 < 4; ++i2) {
      __builtin_amdgcn_global_load_lds(
          (const __attribute__((address_space(1))) u32*)(src + (i2 << 10) + (lane << 4)),
          (__attribute__((address_space(3))) u32*)(dstb + (i2 << 10)),
          16, 0, 0);
    }
  };
  auto blendA = [&](int tt) {      // packed f32x2 blend -> bf16 ds_write
    int k = tt >> 2;
    f32x4 w = *(const f32x4*)&pwt[k][pxs][0];
    f32x2 w0 = {w[0], w[0]}, w1 = {w[1], w[1]};
    f32x2 w2 = {w[2], w[2]}, w3 = {w[3], w[3]};
    char* dst = (char*)&ar.m.A[tt & 1][0][0] + pxs * 128;
    int sw = (pxs & 7) << 4;
#pragma unroll
    for (int g = 0; g < 2; ++g) {
      u32 o4[4];
#pragma unroll
      for (int e = 0; e < 4; ++e) {
        u32 u0 = rA[g * 4 + 0][e], u1 = rA[g * 4 + 1][e];
        u32 u2 = rA[g * 4 + 2][e], u3 = rA[g * 4 + 3][e];
        f32x2 c0 = {__uint_as_float(u0 << 16), __uint_as_float(u0 & 0xffff0000u)};
        f32x2 c1 = {__uint_as_float(u1 << 16), __uint_as_float(u1 & 0xffff0000u)};
        f32x2 c2 = {__uint_as_float(u2 << 16), __uint_as_float(u2 & 0xffff0000u)};
        f32x2 c3 = {__uint_as_float(u3 << 16), __uint_as_float(u3 & 0xffff0000u)};
        f32x2 v = c0 * w0;
        v = c1 * w1 + v;
        v = c2 * w2 + v;
        v = c3 * w3 + v;
        asm("v_cvt_pk_bf16_f32 %0, %1, %2" : "=v"(o4[e]) : "v"(v[0]), "v"(v[1]));
      }
      u32x4 ov = {o4[0], o4[1], o4[2], o4[3]};
      *(u32x4*)(dst + (((gp + g) << 4) ^ sw)) = ov;
    }
  };

  // --- pipeline prologue ---
  issueA(0); FENCE();
  issueB(0, 0); FENCE();
  VMCNT(4);                        // A(0) done (B(0) may fly)
  blendA(0);
  FENCE();
  issueA(1); FENCE();
  issueB(1, 1); FENCE();
  VMCNT(12);                       // B(0) landed
  LGKM0();
  __builtin_amdgcn_s_barrier();
  FENCE();

  int bm3 = 0;                     // tt % 3
  for (int tt = 0; tt < 36; ++tt) {
    // --- blend(t+1) early: ds_write latency hides under MFMA(tt) ---
    if (tt < 35) {
      VMCNT(4);                    // A(tt+1) corners done (B(tt+1) may fly)
      blendA(tt + 1);
      FENCE();
    }
    if (tt < 34) {
      issueA(tt + 2); FENCE();
      int bn = bm3 + 2; if (bn >= 3) bn -= 3;
      issueB(tt + 2, bn); FENCE();
    }
    // --- MFMA(tt) ---
    {
      const char* Ab = (const char*)&ar.m.A[tt & 1][0][0];
      const char* Bb = (const char*)&ar.m.Bt[bm3][0];
      __builtin_amdgcn_s_setprio(1);
#pragma unroll
      for (int s = 0; s < 2; ++s) {
        int kx = (s << 6) + ((lane >> 4) << 4);
        bf16x8 a[4], bb[4];
#pragma unroll
        for (int i = 0; i < 4; ++i) {
          int r16 = (wr << 6) + (i << 4) + (lane & 15);
          a[i] = *(const bf16x8*)(Ab + r16 * 128 + (kx ^ ((r16 & 7) << 4)));
        }
#pragma unroll
        for (int j = 0; j < 4; ++j) {
          int o = obase + (j << 4) + (lane & 15);
          bb[j] = *(const bf16x8*)(Bb + o * 128 + (kx ^ ((o & 7) << 4)));
        }
#pragma unroll
        for (int i = 0; i < 4; ++i)
#pragma unroll
          for (int j = 0; j < 4; ++j)
            acc[i][j] = __builtin_amdgcn_mfma_f32_16x16x32_bf16(a[i], bb[j], acc[i][j], 0, 0, 0);
      }
      __builtin_amdgcn_s_setprio(0);
    }
    FENCE();
    if (tt == 34) { VMCNT(0); }    // force B(35) before its barrier
    else if (tt < 34) { VMCNT(12); } // B(tt+1) landed; keep t+2 in flight
    LGKM0();
    __builtin_amdgcn_s_barrier();
    FENCE();
    bm3 = (bm3 == 2) ? 0 : bm3 + 1;
  }

  // --- GroupNorm partial sums (D: col=lane&15 -> o, row=(lane>>4)*4+r -> px) ---
#pragma unroll
  for (int j = 0; j < 4; ++j) {
    float s1 = 0.f, s2 = 0.f;
#pragma unroll
    for (int i = 0; i < 4; ++i)
#pragma unroll
      for (int r = 0; r < 4; ++r) {
        float v = acc[i][j][r];
        s1 += v;
        s2 += v * v;
      }
    s1 += __shfl_xor(s1, 1, 64);  s2 += __shfl_xor(s2, 1, 64);
    s1 += __shfl_xor(s1, 2, 64);  s2 += __shfl_xor(s2, 2, 64);
    s1 += __shfl_xor(s1, 4, 64);  s2 += __shfl_xor(s2, 4, 64);
    s1 += __shfl_xor(s1, 16, 64); s2 += __shfl_xor(s2, 16, 64);
    s1 += __shfl_xor(s1, 32, 64); s2 += __shfl_xor(s2, 32, 64);
    if ((lane & 0x37) == 0) {     // lanes 0 and 8: one per 8-channel group
      int g = (obase + (j << 4) + (lane & 15)) >> 3;
      atomicAdd(&stats[((b << 5) + g) * 2 + 0], s1);
      atomicAdd(&stats[((b << 5) + g) * 2 + 1], s2);
    }
  }

  // --- acc -> ytile[o][px] bf16 -> yb[b][o][px] ---
#pragma unroll
  for (int i = 0; i < 4; ++i)
#pragma unroll
    for (int j = 0; j < 4; ++j) {
      int o = obase + (j << 4) + (lane & 15);
      int pxr = (wr << 6) + (i << 4) + ((lane >> 4) << 2);
      u32 wv0, wv1;
      asm("v_cvt_pk_bf16_f32 %0, %1, %2" : "=v"(wv0) : "v"(acc[i][j][0]), "v"(acc[i][j][1]));
      asm("v_cvt_pk_bf16_f32 %0, %1, %2" : "=v"(wv1) : "v"(acc[i][j][2]), "v"(acc[i][j][3]));
      u32x2 wv = {wv0, wv1};
      *(u32x2*)((char*)ar.ytile + o * 272 + pxr * 2) = wv;
    }
  __syncthreads();
  {
    int o = t >> 1, half = t & 1;
    const char* srcb = (const char*)ar.ytile + o * 272 + (half << 7);
    unsigned short* dst = yb + (((size_t)(b * 256 + o)) << 12) + pxbase + (half << 6);
#pragma unroll
    for (int qq = 0; qq < 8; ++qq)
      *(u32x4*)((char*)dst + (qq << 4)) = *(const u32x4*)(srcb + (qq << 4));
  }
}

// ---------------------------------------------------------------------------
// K5: GroupNorm finalize + Mish — pure streaming.
// ---------------------------------------------------------------------------
__global__ __launch_bounds__(256) void gn_mish(const unsigned short* __restrict__ yb,
                                               const float* __restrict__ stats,
                                               const float* __restrict__ gamma,
                                               const float* __restrict__ beta,
                                               float* __restrict__ out) {
  int v = blockIdx.x * 512 + threadIdx.x;
#pragma unroll
  for (int it = 0; it < 2; ++it, v += 256) {
    int o = (v >> 9) & 255;
    int b = v >> 17;
    float s1 = stats[((b << 5) + (o >> 3)) * 2 + 0];
    float s2 = stats[((b << 5) + (o >> 3)) * 2 + 1];
    float mean = s1 * (1.f / 32768.f);
    float var = s2 * (1.f / 32768.f) - mean * mean;
    float rstd = rsqrtf(var + 1e-5f);
    float ga = gamma[o] * rstd, be = beta[o] - mean * gamma[o] * rstd;
    u32x4 u = *(const u32x4*)(yb + ((size_t)v << 3));
    float res[8];
#pragma unroll
    for (int e = 0; e < 4; ++e) {
      float va = __uint_as_float(u[e] << 16);
      float vb = __uint_as_float(u[e] & 0xffff0000u);
      float v0 = fmaf(va, ga, be);
      float v1 = fmaf(vb, ga, be);
      float e0 = expf(fminf(v0, 15.f));
      float e1 = expf(fminf(v1, 15.f));
      float n0 = e0 * (e0 + 2.f);
      float n1 = e1 * (e1 + 2.f);
      float m0 = v0 * (n0 / (n0 + 2.f));
      float m1 = v1 * (n1 / (n1 + 2.f));
      if (v0 > 15.f) m0 = v0;
      if (v1 > 15.f) m1 = v1;
      res[2 * e] = m0;
      res[2 * e + 1] = m1;
    }
    f32x4 o0 = {res[0], res[1], res[2], res[3]};
    f32x4 o1 = {res[4], res[5], res[6], res[7]};
    float* dst = out + ((size_t)v << 3);
    *(f32x4*)dst = o0;
    *((f32x4*)dst + 1) = o1;
  }
}

// ---------------------------------------------------------------------------
extern "C" void kernel_launch(void* const* d_in, const int* in_sizes, int n_in,
                              void* d_out, int out_size, void* d_ws, size_t ws_size,
                              hipStream_t stream) {
  const float* x     = (const float*)d_in[0];
  const float* w_off = (const float*)d_in[1];
  const float* b_off = (const float*)d_in[2];
  const float* w_dcn = (const float*)d_in[3];
  const float* gamma = (const float*)d_in[4];
  const float* beta  = (const float*)d_in[5];
  float* out = (float*)d_out;
  char* ws = (char*)d_ws;
  unsigned short* xT   = (unsigned short*)(ws);              // 16,777,216 B (bf16)
  unsigned short* yb   = (unsigned short*)(ws + 16777216);   // 16,777,216 B (bf16)
  float* offs          = (float*)(ws + 33554432);            //  2,359,296 B
  unsigned short* wT4  = (unsigned short*)(ws + 35913728);   //  1,179,648 B
  unsigned short* wOffT= (unsigned short*)(ws + 37093376);   //    147,456 B
  float* stats         = (float*)(ws + 37240832);            //      2,048 B
  prep<<<dim3(2594), dim3(256), 0, stream>>>(w_dcn, w_off, wT4, wOffT, stats);
  transpose_x<<<dim3(2048), dim3(256), 0, stream>>>(x, xT);
  conv_offset_mfma<<<dim3(512), dim3(256), 0, stream>>>(xT, wOffT, offs);
  dcn_main<<<dim3(256), dim3(512), 0, stream>>>(xT, offs, b_off, wT4, yb, stats);
  gn_mish<<<dim3(2048), dim3(256), 0, stream>>>(yb, stats, gamma, beta, out);
}

// Round 13
// 115.244 us; speedup vs baseline: 2.1674x; 1.0912x over previous
//
#include <hip/hip_runtime.h>
#include <hip/hip_bf16.h>
#include <math.h>

typedef __bf16 bf16x8 __attribute__((ext_vector_type(8)));
typedef float f32x4 __attribute__((ext_vector_type(4)));
typedef float f32x2 __attribute__((ext_vector_type(2)));
typedef unsigned int u32;
typedef u32 u32x4 __attribute__((ext_vector_type(4)));
typedef u32 u32x2 __attribute__((ext_vector_type(2)));

// Problem constants: B=8, C=256, H=W=64, O=256, K=9, GN groups=32 (8 ch each)
// xT layout (granule-major): [b][cg=32][pix=4096][8ch] bf16; granule = 16B.

#define FENCE() __builtin_amdgcn_sched_barrier(0)
#define VMCNT(n) do { asm volatile("s_waitcnt vmcnt(" #n ")" ::: "memory"); FENCE(); } while (0)
#define LGKM0() do { asm volatile("s_waitcnt lgkmcnt(0)" ::: "memory"); FENCE(); } while (0)

__device__ inline u32 pack2bf16(float a, float b) {
  u32 ua = __float_as_uint(a);
  u32 ub = __float_as_uint(b);
  ua += 0x7fffu + ((ua >> 16) & 1u);   // RNE
  ub += 0x7fffu + ((ub >> 16) & 1u);
  return (ua >> 16) | (ub & 0xffff0000u);
}

// ---------------------------------------------------------------------------
// K0: prep — pack w_dcn into swizzled bf16 tiles, pack w_off into swizzled
// bf16 tiles (O padded 18->32), zero stats.
// ---------------------------------------------------------------------------
__global__ void prep(const float* __restrict__ w_dcn, const float* __restrict__ w_off,
                     unsigned short* __restrict__ wT4, unsigned short* __restrict__ wOffT,
                     float* __restrict__ stats) {
  size_t id = (size_t)blockIdx.x * 256 + threadIdx.x;
  if (id < 589824) {               // 256 o * 2304 ck
    int o  = (int)(id / 2304);
    int ck = (int)(id % 2304);     // ck = k*256 + c
    int k = ck >> 8, c = ck & 255;
    float v = w_dcn[(size_t)(o * 256 + c) * 9 + k];
    u32 uv = __float_as_uint(v);
    uv += 0x7fffu + ((uv >> 16) & 1u);
    int tile = ck >> 6, kk = ck & 63;
    int lin = o * 128 + kk * 2;
    int swz = lin ^ ((o & 7) << 4);
    *(unsigned short*)((char*)wT4 + (size_t)tile * 32768 + swz) = (unsigned short)(uv >> 16);
  } else if (id < 663552) {        // 36 tiles * 32 o * 64 kk = 73728
    int r = (int)(id - 589824);
    int tile = r >> 11;            // k*4 + cc
    int rr = r & 2047;
    int o = rr >> 6, kk = rr & 63;
    int k = tile >> 2, cc = tile & 3;
    int c = (cc << 6) + kk;
    float v = (o < 18) ? w_off[(size_t)(o * 256 + c) * 9 + k] : 0.f;
    u32 uv = __float_as_uint(v);
    uv += 0x7fffu + ((uv >> 16) & 1u);
    int swz = (o * 128 + kk * 2) ^ ((o & 7) << 4);
    *(unsigned short*)((char*)wOffT + (size_t)tile * 4096 + swz) = (unsigned short)(uv >> 16);
  } else if (id < 664064) {        // zero stats: 512 floats
    stats[id - 663552] = 0.f;
  }
}

// ---------------------------------------------------------------------------
// K1: transpose x [B][C][H][W] -> xT granule-major [b][cg][pix][8ch] bf16
// ---------------------------------------------------------------------------
__global__ __launch_bounds__(256) void transpose_x(const float* __restrict__ x,
                                                   unsigned short* __restrict__ xT) {
  __shared__ float tl[64][65];
  int bx = blockIdx.x;
  int b = bx >> 8;
  int y = (bx >> 2) & 63;
  int cb = (bx & 3) << 6;          // 64-ch chunk base
  int t = threadIdx.x;
  int xi = t & 63, cr = t >> 6;
  size_t base = (((size_t)(b * 256 + cb) * 64 + y) << 6);
#pragma unroll
  for (int rep = 0; rep < 16; ++rep) {
    int cl = rep * 4 + cr;
    tl[cl][xi] = x[base + (size_t)cl * 4096 + xi];
  }
  __syncthreads();
  int xw = t & 63, cpair = t >> 6;   // cpair in [0,4)
#pragma unroll
  for (int r = 0; r < 2; ++r) {
    int cgl = cpair * 2 + r;         // local granule in this 64-ch chunk
    int cg = (cb >> 3) + cgl;
    u32 pk4[4];
#pragma unroll
    for (int i = 0; i < 4; ++i)
      pk4[i] = pack2bf16(tl[cgl * 8 + 2 * i][xw], tl[cgl * 8 + 2 * i + 1][xw]);
    u32x4 v = {pk4[0], pk4[1], pk4[2], pk4[3]};
    *(u32x4*)((char*)xT + (((size_t)b << 21)) + ((size_t)cg << 16) + ((y << 6) + xw) * 16) = v;
  }
}

// ---------------------------------------------------------------------------
// K2: offset conv — DIRECT-A GEMM (kept from R12: proved fast). A-frags load
// straight from granule-major xT into MFMA registers; 4 independent waves,
// per-wave B dbuf via gload_lds + counted vmcnt, zero loop barriers.
// ---------------------------------------------------------------------------
__global__ __launch_bounds__(256) void conv_offset_mfma(
    const unsigned short* __restrict__ xT, const unsigned short* __restrict__ wOffT,
    float* __restrict__ offs) {
  __shared__ union {
    unsigned short Bo[4][2][2048];   // [wave][dbuf][32o x 64kk] = 32 KB
    float red[4][64][32];            // [wave][px][o] partials   = 32 KB
  } sm;
  const int bx = blockIdx.x;
  const int lb = ((bx & 7) << 6) + (bx >> 3);   // XCD x -> image x
  const int b = lb >> 6;
  const int row = lb & 63;
  const int t = threadIdx.x;
  const int lane = t & 63, w = t >> 6;          // 4 waves, wave = c-chunk w
  const char* xTbB = (const char*)xT + ((size_t)b << 21);

  f32x4 acc[4][2];
#pragma unroll
  for (int i = 0; i < 4; ++i)
#pragma unroll
    for (int j = 0; j < 2; ++j) {
      f32x4 z = {0.f, 0.f, 0.f, 0.f};
      acc[i][j] = z;
    }

  auto stageB = [&](int k, int d) {   // tile (k*4 + w), 4 KB, own LDS slice
    const char* src = (const char*)wOffT + ((size_t)((k << 2) + w) << 12);
    char* dstb = (char*)&sm.Bo[w][d][0];
#pragma unroll
    for (int i2 = 0; i2 < 4; ++i2) {
      __builtin_amdgcn_global_load_lds(
          (const __attribute__((address_space(1))) u32*)(src + (i2 << 10) + (lane << 4)),
          (__attribute__((address_space(3))) u32*)(dstb + (i2 << 10)),
          16, 0, 0);
    }
  };

  stageB(0, 0);
  u32x4 rA[8];
  const u32x4 zv = {0u, 0u, 0u, 0u};

  for (int k = 0; k < 9; ++k) {
    int ky = k / 3, kxv = k - ky * 3;
    int rowp = row - 1 + ky;
    bool rok = ((unsigned)rowp < 64u);   // block-uniform
    bool ok[4];
    if (rok) {
      int pix[4];
#pragma unroll
      for (int pg = 0; pg < 4; ++pg) {
        int xs = (pg << 4) + (lane & 15) + kxv - 1;
        ok[pg] = ((unsigned)xs < 64u);
        int xc = min(max(xs, 0), 63);
        pix[pg] = (rowp << 6) + xc;
      }
#pragma unroll
      for (int s = 0; s < 2; ++s) {
        const char* base = xTbB + ((size_t)((w << 3) + (s << 2) + (lane >> 4)) << 16);
#pragma unroll
        for (int pg = 0; pg < 4; ++pg)
          rA[s * 4 + pg] = *(const u32x4*)(base + ((size_t)pix[pg] << 4));
      }
    }
    if (k < 8) stageB(k + 1, (k + 1) & 1);
    VMCNT(4);                            // A(k) + B(k) done; B(k+1) in flight
    if (rok) {
      const char* Bb = (const char*)&sm.Bo[w][k & 1][0];
#pragma unroll
      for (int s = 0; s < 2; ++s) {
        bf16x8 bb[2];
        int kx = (s << 6) + ((lane >> 4) << 4);
#pragma unroll
        for (int j = 0; j < 2; ++j) {
          int o = (j << 4) + (lane & 15);
          bb[j] = *(const bf16x8*)(Bb + o * 128 + (kx ^ ((o & 7) << 4)));
        }
#pragma unroll
        for (int pg = 0; pg < 4; ++pg) {
          u32x4 av = ok[pg] ? rA[s * 4 + pg] : zv;
          bf16x8 af = __builtin_bit_cast(bf16x8, av);
#pragma unroll
          for (int j = 0; j < 2; ++j)
            acc[pg][j] = __builtin_amdgcn_mfma_f32_16x16x32_bf16(af, bb[j], acc[pg][j], 0, 0, 0);
        }
      }
    }
  }

  // epilogue: partials into own LDS slice (aliases own Bo), reduce, write offs
#pragma unroll
  for (int pg = 0; pg < 4; ++pg)
#pragma unroll
    for (int j = 0; j < 2; ++j)
#pragma unroll
      for (int r = 0; r < 4; ++r) {
        int px = (pg << 4) + ((lane >> 4) << 2) + r;
        int o = (j << 4) + (lane & 15);
        sm.red[w][px][o] = acc[pg][j][r];
      }
  __syncthreads();
  {
    int px = t >> 2, oq = (t & 3) << 3;
#pragma unroll
    for (int e = 0; e < 8; ++e) {
      int o = oq + e;
      if (o < 18) {
        float sv = sm.red[0][px][o] + sm.red[1][px][o]
                 + sm.red[2][px][o] + sm.red[3][px][o];
        offs[((size_t)b * 4096 + (row << 6) + px) * 18 + o] = sv;
      }
    }
  }
}

// ---------------------------------------------------------------------------
// K4: main fused kernel — R11 schedule restored (best measured): per step
// MFMA(tt) -> vmcnt(4) blend(t+1) -> issueA/B(t+2) -> vmcnt(12) -> barrier.
// Counted vmcnt, never 0 in loop; B tri-buffered.
// block = 128 px x 256 O, 512 thr, 8 waves (wave = 64px x 64o, acc[4][4]).
// ---------------------------------------------------------------------------
union ArenaM {
  struct {
    unsigned short A[2][128][64];   //  32,768 B (byte ^= (row&7)<<4)
    unsigned short Bt[3][16384];    //  98,304 B ([256 o][64 kk] swz)
  } m;
  unsigned short ytile[256][136];   //  69,632 B (o-major epilogue buffer)
};

__global__ __launch_bounds__(512) void dcn_main(
    const unsigned short* __restrict__ xT, const float* __restrict__ offs,
    const float* __restrict__ boff, const unsigned short* __restrict__ wT4,
    unsigned short* __restrict__ yb, float* __restrict__ stats) {
  __shared__ ArenaM ar;
  __shared__ u32 pcor[9][128][2];   //  9,216 B (c01, c23 per (k,px))
  __shared__ float pwt[9][128][4];  // 18,432 B (4 bilinear weights)

  const int bx = blockIdx.x;
  const int lb = ((bx & 7) << 5) + (bx >> 3);   // XCD x -> image x
  const int b = lb >> 5;
  const int pxbase = (lb & 31) << 7;            // 128-px group (2 rows)
  const int t = threadIdx.x;
  const int lane = t & 63, wid = t >> 6;        // wid 0..7
  const char* xTbB = (const char*)xT + ((size_t)b << 21);
  const int pxs = ((wid & 1) << 6) + lane;      // staging px (lane-consec)
  const int gp = (wid >> 1) << 1;               // granules gp, gp+1
  const int wr = wid >> 2, wc = wid & 3;
  const int obase = wc << 6;

  // --- prologue: per-(k,px) sampling params into LDS ---
  for (int idx = t; idx < 1152; idx += 512) {
    int k = idx >> 7, px = idx & 127;
    int pxg = pxbase + px;
    int yy = pxg >> 6, xx = pxg & 63;
    int ky = k / 3, kx = k - ky * 3;
    const float* op = offs + ((size_t)b * 4096 + pxg) * 18 + k * 2;
    float py = op[0] + boff[k * 2] + (float)(yy - 1 + ky);
    float pxf = op[1] + boff[k * 2 + 1] + (float)(xx - 1 + kx);
    float fy = floorf(py), fx = floorf(pxf);
    float dy = py - fy, dx = pxf - fx;
    int y0 = (int)fy, x0 = (int)fx;
    int y1 = y0 + 1, x1 = x0 + 1;
    float vy0 = ((unsigned)y0 < 64u) ? 1.f : 0.f;
    float vy1 = ((unsigned)y1 < 64u) ? 1.f : 0.f;
    float vx0 = ((unsigned)x0 < 64u) ? 1.f : 0.f;
    float vx1 = ((unsigned)x1 < 64u) ? 1.f : 0.f;
    int y0c = min(max(y0, 0), 63), y1c = min(max(y1, 0), 63);
    int x0c = min(max(x0, 0), 63), x1c = min(max(x1, 0), 63);
    pcor[k][px][0] = (u32)((y0c << 6) + x0c) | ((u32)((y0c << 6) + x1c) << 16);
    pcor[k][px][1] = (u32)((y1c << 6) + x0c) | ((u32)((y1c << 6) + x1c) << 16);
    pwt[k][px][0] = (1.f - dy) * (1.f - dx) * vy0 * vx0;
    pwt[k][px][1] = (1.f - dy) * dx * vy0 * vx1;
    pwt[k][px][2] = dy * (1.f - dx) * vy1 * vx0;
    pwt[k][px][3] = dy * dx * vy1 * vx1;
  }

  f32x4 acc[4][4];
#pragma unroll
  for (int i = 0; i < 4; ++i)
#pragma unroll
    for (int j = 0; j < 4; ++j) {
      f32x4 z = {0.f, 0.f, 0.f, 0.f};
      acc[i][j] = z;
    }

  __syncthreads();                 // params ready

  u32x4 rA[8];                     // in-flight corners: 2 granules x 4 corners

  auto issueA = [&](int tt) {      // 8 VMEM loads, coalesced
    int k = tt >> 2, cc = tt & 3;
    u32 c01 = pcor[k][pxs][0], c23 = pcor[k][pxs][1];
    const char* p0 = xTbB + ((size_t)((cc << 3) + gp) << 16);
#pragma unroll
    for (int g = 0; g < 2; ++g) {
      const char* bgp = p0 + ((size_t)g << 16);
      rA[g * 4 + 0] = *(const u32x4*)(bgp + ((size_t)(c01 & 0xffffu) << 4));
      rA[g * 4 + 1] = *(const u32x4*)(bgp + ((size_t)(c01 >> 16) << 4));
      rA[g * 4 + 2] = *(const u32x4*)(bgp + ((size_t)(c23 & 0xffffu) << 4));
      rA[g * 4 + 3] = *(const u32x4*)(bgp + ((size_t)(c23 >> 16) << 4));
    }
  };
  auto issueB = [&](int tt, int bufi) {   // 4 gload_lds, 4KB slice per wave
    const char* src = (const char*)wT4 + ((size_t)tt << 15) + (wid << 12);
    char* dstb = (char*)&ar.m.Bt[bufi][0] + (wid << 12);
#pragma unroll
    for (int i2 = 0; i2 < 4; ++i2) {
      __builtin_amdgcn_global_load_lds(
          (const __attribute__((address_space(1))) u32*)(src + (i2 << 10) + (lane << 4)),
          (__attribute__((address_space(3))) u32*)(dstb + (i2 << 10)),
          16, 0, 0);
    }
  };
  auto blendA = [&](int tt) {      // blend rA -> bf16, swizzled ds_write
    int k = tt >> 2;
    f32x4 w = *(const f32x4*)&pwt[k][pxs][0];
    char* dst = (char*)&ar.m.A[tt & 1][0][0] + pxs * 128;
    int sw = (pxs & 7) << 4;
#pragma unroll
    for (int g = 0; g < 2; ++g) {
      u32 o4[4];
#pragma unroll
      for (int e = 0; e < 4; ++e) {
        u32 u0 = rA[g * 4 + 0][e], u1 = rA[g * 4 + 1][e];
        u32 u2 = rA[g * 4 + 2][e], u3 = rA[g * 4 + 3][e];
        float lo = w[0] * __uint_as_float(u0 << 16);
        lo = fmaf(w[1], __uint_as_float(u1 << 16), lo);
        lo = fmaf(w[2], __uint_as_float(u2 << 16), lo);
        lo = fmaf(w[3], __uint_as_float(u3 << 16), lo);
        float hi = w[0] * __uint_as_float(u0 & 0xffff0000u);
        hi = fmaf(w[1], __uint_as_float(u1 & 0xffff0000u), hi);
        hi = fmaf(w[2], __uint_as_float(u2 & 0xffff0000u), hi);
        hi = fmaf(w[3], __uint_as_float(u3 & 0xffff0000u), hi);
        asm("v_cvt_pk_bf16_f32 %0, %1, %2" : "=v"(o4[e]) : "v"(lo), "v"(hi));
      }
      u32x4 ov = {o4[0], o4[1], o4[2], o4[3]};
      *(u32x4*)(dst + (((gp + g) << 4) ^ sw)) = ov;
    }
  };

  // --- pipeline prologue ---
  issueA(0); FENCE();
  issueB(0, 0); FENCE();
  VMCNT(4);                        // A(0) done (B(0) may fly)
  blendA(0);
  FENCE();
  issueA(1); FENCE();
  issueB(1, 1); FENCE();
  VMCNT(12);                       // own B(0) landed
  LGKM0();
  __builtin_amdgcn_s_barrier();

  int bm3 = 0;                     // tt % 3
  for (int tt = 0; tt < 36; ++tt) {
    // --- MFMA(tt) ---
    {
      const char* Ab = (const char*)&ar.m.A[tt & 1][0][0];
      const char* Bb = (const char*)&ar.m.Bt[bm3][0];
      __builtin_amdgcn_s_setprio(1);
#pragma unroll
      for (int s = 0; s < 2; ++s) {
        int kx = (s << 6) + ((lane >> 4) << 4);
        bf16x8 a[4], bb[4];
#pragma unroll
        for (int i = 0; i < 4; ++i) {
          int r16 = (wr << 6) + (i << 4) + (lane & 15);
          a[i] = *(const bf16x8*)(Ab + r16 * 128 + (kx ^ ((r16 & 7) << 4)));
        }
#pragma unroll
        for (int j = 0; j < 4; ++j) {
          int o = obase + (j << 4) + (lane & 15);
          bb[j] = *(const bf16x8*)(Bb + o * 128 + (kx ^ ((o & 7) << 4)));
        }
#pragma unroll
        for (int i = 0; i < 4; ++i)
#pragma unroll
          for (int j = 0; j < 4; ++j)
            acc[i][j] = __builtin_amdgcn_mfma_f32_16x16x32_bf16(a[i], bb[j], acc[i][j], 0, 0, 0);
      }
      __builtin_amdgcn_s_setprio(0);
    }
    FENCE();
    if (tt < 35) {
      VMCNT(4);                    // A(tt+1) corners done (B(tt+1) may fly)
      blendA(tt + 1);
      FENCE();
      if (tt < 34) {
        issueA(tt + 2); FENCE();
        int bn = bm3 + 2; if (bn >= 3) bn -= 3;
        issueB(tt + 2, bn); FENCE();
      }
    }
    if (tt == 34) { VMCNT(0); }    // force B(35) before last barrier
    else { VMCNT(12); }            // own B(tt+1) landed; keep t+2 in flight
    LGKM0();
    __builtin_amdgcn_s_barrier();
    FENCE();
    bm3 = (bm3 == 2) ? 0 : bm3 + 1;
  }

  // --- GroupNorm partial sums (D: col=lane&15 -> o, row=(lane>>4)*4+r -> px) ---
#pragma unroll
  for (int j = 0; j < 4; ++j) {
    float s1 = 0.f, s2 = 0.f;
#pragma unroll
    for (int i = 0; i < 4; ++i)
#pragma unroll
      for (int r = 0; r < 4; ++r) {
        float v = acc[i][j][r];
        s1 += v;
        s2 += v * v;
      }
    s1 += __shfl_xor(s1, 1, 64);  s2 += __shfl_xor(s2, 1, 64);
    s1 += __shfl_xor(s1, 2, 64);  s2 += __shfl_xor(s2, 2, 64);
    s1 += __shfl_xor(s1, 4, 64);  s2 += __shfl_xor(s2, 4, 64);
    s1 += __shfl_xor(s1, 16, 64); s2 += __shfl_xor(s2, 16, 64);
    s1 += __shfl_xor(s1, 32, 64); s2 += __shfl_xor(s2, 32, 64);
    if ((lane & 0x37) == 0) {     // lanes 0 and 8: one per 8-channel group
      int g = (obase + (j << 4) + (lane & 15)) >> 3;
      atomicAdd(&stats[((b << 5) + g) * 2 + 0], s1);
      atomicAdd(&stats[((b << 5) + g) * 2 + 1], s2);
    }
  }

  // --- acc -> ytile[o][px] bf16 -> yb[b][o][px] ---
#pragma unroll
  for (int i = 0; i < 4; ++i)
#pragma unroll
    for (int j = 0; j < 4; ++j) {
      int o = obase + (j << 4) + (lane & 15);
      int pxr = (wr << 6) + (i << 4) + ((lane >> 4) << 2);
      u32 wv0, wv1;
      asm("v_cvt_pk_bf16_f32 %0, %1, %2" : "=v"(wv0) : "v"(acc[i][j][0]), "v"(acc[i][j][1]));
      asm("v_cvt_pk_bf16_f32 %0, %1, %2" : "=v"(wv1) : "v"(acc[i][j][2]), "v"(acc[i][j][3]));
      u32x2 wv = {wv0, wv1};
      *(u32x2*)((char*)ar.ytile + o * 272 + pxr * 2) = wv;
    }
  __syncthreads();
  {
    int o = t >> 1, half = t & 1;
    const char* srcb = (const char*)ar.ytile + o * 272 + (half << 7);
    unsigned short* dst = yb + (((size_t)(b * 256 + o)) << 12) + pxbase + (half << 6);
#pragma unroll
    for (int qq = 0; qq < 8; ++qq)
      *(u32x4*)((char*)dst + (qq << 4)) = *(const u32x4*)(srcb + (qq << 4));
  }
}

// ---------------------------------------------------------------------------
// K5: GroupNorm finalize + Mish — pure streaming.
// ---------------------------------------------------------------------------
__global__ __launch_bounds__(256) void gn_mish(const unsigned short* __restrict__ yb,
                                               const float* __restrict__ stats,
                                               const float* __restrict__ gamma,
                                               const float* __restrict__ beta,
                                               float* __restrict__ out) {
  int v = blockIdx.x * 512 + threadIdx.x;
#pragma unroll
  for (int it = 0; it < 2; ++it, v += 256) {
    int o = (v >> 9) & 255;
    int b = v >> 17;
    float s1 = stats[((b << 5) + (o >> 3)) * 2 + 0];
    float s2 = stats[((b << 5) + (o >> 3)) * 2 + 1];
    float mean = s1 * (1.f / 32768.f);
    float var = s2 * (1.f / 32768.f) - mean * mean;
    float rstd = rsqrtf(var + 1e-5f);
    float ga = gamma[o] * rstd, be = beta[o] - mean * gamma[o] * rstd;
    u32x4 u = *(const u32x4*)(yb + ((size_t)v << 3));
    float res[8];
#pragma unroll
    for (int e = 0; e < 4; ++e) {
      float va = __uint_as_float(u[e] << 16);
      float vb = __uint_as_float(u[e] & 0xffff0000u);
      float v0 = fmaf(va, ga, be);
      float v1 = fmaf(vb, ga, be);
      float e0 = expf(fminf(v0, 15.f));
      float e1 = expf(fminf(v1, 15.f));
      float n0 = e0 * (e0 + 2.f);
      float n1 = e1 * (e1 + 2.f);
      float m0 = v0 * (n0 / (n0 + 2.f));
      float m1 = v1 * (n1 / (n1 + 2.f));
      if (v0 > 15.f) m0 = v0;
      if (v1 > 15.f) m1 = v1;
      res[2 * e] = m0;
      res[2 * e + 1] = m1;
    }
    f32x4 o0 = {res[0], res[1], res[2], res[3]};
    f32x4 o1 = {res[4], res[5], res[6], res[7]};
    float* dst = out + ((size_t)v << 3);
    *(f32x4*)dst = o0;
    *((f32x4*)dst + 1) = o1;
  }
}

// ---------------------------------------------------------------------------
extern "C" void kernel_launch(void* const* d_in, const int* in_sizes, int n_in,
                              void* d_out, int out_size, void* d_ws, size_t ws_size,
                              hipStream_t stream) {
  const float* x     = (const float*)d_in[0];
  const float* w_off = (const float*)d_in[1];
  const float* b_off = (const float*)d_in[2];
  const float* w_dcn = (const float*)d_in[3];
  const float* gamma = (const float*)d_in[4];
  const float* beta  = (const float*)d_in[5];
  float* out = (float*)d_out;
  char* ws = (char*)d_ws;
  unsigned short* xT   = (unsigned short*)(ws);              // 16,777,216 B (bf16)
  unsigned short* yb   = (unsigned short*)(ws + 16777216);   // 16,777,216 B (bf16)
  float* offs          = (float*)(ws + 33554432);            //  2,359,296 B
  unsigned short* wT4  = (unsigned short*)(ws + 35913728);   //  1,179,648 B
  unsigned short* wOffT= (unsigned short*)(ws + 37093376);   //    147,456 B
  float* stats         = (float*)(ws + 37240832);            //      2,048 B
  prep<<<dim3(2594), dim3(256), 0, stream>>>(w_dcn, w_off, wT4, wOffT, stats);
  transpose_x<<<dim3(2048), dim3(256), 0, stream>>>(x, xT);
  conv_offset_mfma<<<dim3(512), dim3(256), 0, stream>>>(xT, wOffT, offs);
  dcn_main<<<dim3(256), dim3(512), 0, stream>>>(xT, offs, b_off, wT4, yb, stats);
  gn_mish<<<dim3(2048), dim3(256), 0, stream>>>(yb, stats, gamma, beta, out);
}

// Round 15
// 112.237 us; speedup vs baseline: 2.2254x; 1.0268x over previous
//
#include <hip/hip_runtime.h>
#include <hip/hip_bf16.h>
#include <math.h>

typedef __bf16 bf16x8 __attribute__((ext_vector_type(8)));
typedef float f32x4 __attribute__((ext_vector_type(4)));
typedef float f32x2 __attribute__((ext_vector_type(2)));
typedef unsigned int u32;
typedef u32 u32x4 __attribute__((ext_vector_type(4)));
typedef u32 u32x2 __attribute__((ext_vector_type(2)));

// Problem constants: B=8, C=256, H=W=64, O=256, K=9, GN groups=32 (8 ch each)
// xT layout (granule-major): [b][cg=32][pix=4096][8ch] bf16; granule = 16B.

#define FENCE() __builtin_amdgcn_sched_barrier(0)
#define VMCNT(n) do { asm volatile("s_waitcnt vmcnt(" #n ")" ::: "memory"); FENCE(); } while (0)
#define LGKM0() do { asm volatile("s_waitcnt lgkmcnt(0)" ::: "memory"); FENCE(); } while (0)

__device__ inline u32 pack2bf16(float a, float b) {
  u32 ua = __float_as_uint(a);
  u32 ub = __float_as_uint(b);
  ua += 0x7fffu + ((ua >> 16) & 1u);   // RNE
  ub += 0x7fffu + ((ub >> 16) & 1u);
  return (ua >> 16) | (ub & 0xffff0000u);
}

// ---------------------------------------------------------------------------
// K0: prep — pack w_dcn into swizzled bf16 tiles, pack w_off into swizzled
// bf16 tiles (O padded 18->32), zero stats.
// ---------------------------------------------------------------------------
__global__ void prep(const float* __restrict__ w_dcn, const float* __restrict__ w_off,
                     unsigned short* __restrict__ wT4, unsigned short* __restrict__ wOffT,
                     float* __restrict__ stats) {
  size_t id = (size_t)blockIdx.x * 256 + threadIdx.x;
  if (id < 589824) {               // 256 o * 2304 ck
    int o  = (int)(id / 2304);
    int ck = (int)(id % 2304);     // ck = k*256 + c
    int k = ck >> 8, c = ck & 255;
    float v = w_dcn[(size_t)(o * 256 + c) * 9 + k];
    u32 uv = __float_as_uint(v);
    uv += 0x7fffu + ((uv >> 16) & 1u);
    int tile = ck >> 6, kk = ck & 63;
    int lin = o * 128 + kk * 2;
    int swz = lin ^ ((o & 7) << 4);
    *(unsigned short*)((char*)wT4 + (size_t)tile * 32768 + swz) = (unsigned short)(uv >> 16);
  } else if (id < 663552) {        // 36 tiles * 32 o * 64 kk = 73728
    int r = (int)(id - 589824);
    int tile = r >> 11;            // k*4 + cc
    int rr = r & 2047;
    int o = rr >> 6, kk = rr & 63;
    int k = tile >> 2, cc = tile & 3;
    int c = (cc << 6) + kk;
    float v = (o < 18) ? w_off[(size_t)(o * 256 + c) * 9 + k] : 0.f;
    u32 uv = __float_as_uint(v);
    uv += 0x7fffu + ((uv >> 16) & 1u);
    int swz = (o * 128 + kk * 2) ^ ((o & 7) << 4);
    *(unsigned short*)((char*)wOffT + (size_t)tile * 4096 + swz) = (unsigned short)(uv >> 16);
  } else if (id < 664064) {        // zero stats: 512 floats
    stats[id - 663552] = 0.f;
  }
}

// ---------------------------------------------------------------------------
// K1: transpose x [B][C][H][W] -> xT granule-major [b][cg][pix][8ch] bf16
// ---------------------------------------------------------------------------
__global__ __launch_bounds__(256) void transpose_x(const float* __restrict__ x,
                                                   unsigned short* __restrict__ xT) {
  __shared__ float tl[64][65];
  int bx = blockIdx.x;
  int b = bx >> 8;
  int y = (bx >> 2) & 63;
  int cb = (bx & 3) << 6;          // 64-ch chunk base
  int t = threadIdx.x;
  int xi = t & 63, cr = t >> 6;
  size_t base = (((size_t)(b * 256 + cb) * 64 + y) << 6);
#pragma unroll
  for (int rep = 0; rep < 16; ++rep) {
    int cl = rep * 4 + cr;
    tl[cl][xi] = x[base + (size_t)cl * 4096 + xi];
  }
  __syncthreads();
  int xw = t & 63, cpair = t >> 6;   // cpair in [0,4)
#pragma unroll
  for (int r = 0; r < 2; ++r) {
    int cgl = cpair * 2 + r;         // local granule in this 64-ch chunk
    int cg = (cb >> 3) + cgl;
    u32 pk4[4];
#pragma unroll
    for (int i = 0; i < 4; ++i)
      pk4[i] = pack2bf16(tl[cgl * 8 + 2 * i][xw], tl[cgl * 8 + 2 * i + 1][xw]);
    u32x4 v = {pk4[0], pk4[1], pk4[2], pk4[3]};
    *(u32x4*)((char*)xT + (((size_t)b << 21)) + ((size_t)cg << 16) + ((y << 6) + xw) * 16) = v;
  }
}

// ---------------------------------------------------------------------------
// K2: offset conv — DIRECT-A GEMM (unchanged from R13).
// ---------------------------------------------------------------------------
__global__ __launch_bounds__(256) void conv_offset_mfma(
    const unsigned short* __restrict__ xT, const unsigned short* __restrict__ wOffT,
    float* __restrict__ offs) {
  __shared__ union {
    unsigned short Bo[4][2][2048];   // [wave][dbuf][32o x 64kk] = 32 KB
    float red[4][64][32];            // [wave][px][o] partials   = 32 KB
  } sm;
  const int bx = blockIdx.x;
  const int lb = ((bx & 7) << 6) + (bx >> 3);   // XCD x -> image x
  const int b = lb >> 6;
  const int row = lb & 63;
  const int t = threadIdx.x;
  const int lane = t & 63, w = t >> 6;          // 4 waves, wave = c-chunk w
  const char* xTbB = (const char*)xT + ((size_t)b << 21);

  f32x4 acc[4][2];
#pragma unroll
  for (int i = 0; i < 4; ++i)
#pragma unroll
    for (int j = 0; j < 2; ++j) {
      f32x4 z = {0.f, 0.f, 0.f, 0.f};
      acc[i][j] = z;
    }

  auto stageB = [&](int k, int d) {   // tile (k*4 + w), 4 KB, own LDS slice
    const char* src = (const char*)wOffT + ((size_t)((k << 2) + w) << 12);
    char* dstb = (char*)&sm.Bo[w][d][0];
#pragma unroll
    for (int i2 = 0; i2 < 4; ++i2) {
      __builtin_amdgcn_global_load_lds(
          (const __attribute__((address_space(1))) u32*)(src + (i2 << 10) + (lane << 4)),
          (__attribute__((address_space(3))) u32*)(dstb + (i2 << 10)),
          16, 0, 0);
    }
  };

  stageB(0, 0);
  u32x4 rA[8];
  const u32x4 zv = {0u, 0u, 0u, 0u};

  for (int k = 0; k < 9; ++k) {
    int ky = k / 3, kxv = k - ky * 3;
    int rowp = row - 1 + ky;
    bool rok = ((unsigned)rowp < 64u);   // block-uniform
    bool ok[4];
    if (rok) {
      int pix[4];
#pragma unroll
      for (int pg = 0; pg < 4; ++pg) {
        int xs = (pg << 4) + (lane & 15) + kxv - 1;
        ok[pg] = ((unsigned)xs < 64u);
        int xc = min(max(xs, 0), 63);
        pix[pg] = (rowp << 6) + xc;
      }
#pragma unroll
      for (int s = 0; s < 2; ++s) {
        const char* base = xTbB + ((size_t)((w << 3) + (s << 2) + (lane >> 4)) << 16);
#pragma unroll
        for (int pg = 0; pg < 4; ++pg)
          rA[s * 4 + pg] = *(const u32x4*)(base + ((size_t)pix[pg] << 4));
      }
    }
    if (k < 8) stageB(k + 1, (k + 1) & 1);
    VMCNT(4);                            // A(k) + B(k) done; B(k+1) in flight
    if (rok) {
      const char* Bb = (const char*)&sm.Bo[w][k & 1][0];
#pragma unroll
      for (int s = 0; s < 2; ++s) {
        bf16x8 bb[2];
        int kx = (s << 6) + ((lane >> 4) << 4);
#pragma unroll
        for (int j = 0; j < 2; ++j) {
          int o = (j << 4) + (lane & 15);
          bb[j] = *(const bf16x8*)(Bb + o * 128 + (kx ^ ((o & 7) << 4)));
        }
#pragma unroll
        for (int pg = 0; pg < 4; ++pg) {
          u32x4 av = ok[pg] ? rA[s * 4 + pg] : zv;
          bf16x8 af = __builtin_bit_cast(bf16x8, av);
#pragma unroll
          for (int j = 0; j < 2; ++j)
            acc[pg][j] = __builtin_amdgcn_mfma_f32_16x16x32_bf16(af, bb[j], acc[pg][j], 0, 0, 0);
        }
      }
    }
  }

  // epilogue: partials into own LDS slice (aliases own Bo), reduce, write offs
#pragma unroll
  for (int pg = 0; pg < 4; ++pg)
#pragma unroll
    for (int j = 0; j < 2; ++j)
#pragma unroll
      for (int r = 0; r < 4; ++r) {
        int px = (pg << 4) + ((lane >> 4) << 2) + r;
        int o = (j << 4) + (lane & 15);
        sm.red[w][px][o] = acc[pg][j][r];
      }
  __syncthreads();
  {
    int px = t >> 2, oq = (t & 3) << 3;
#pragma unroll
    for (int e = 0; e < 8; ++e) {
      int o = oq + e;
      if (o < 18) {
        float sv = sm.red[0][px][o] + sm.red[1][px][o]
                 + sm.red[2][px][o] + sm.red[3][px][o];
        offs[((size_t)b * 4096 + (row << 6) + px) * 18 + o] = sv;
      }
    }
  }
}

// ---------------------------------------------------------------------------
// K4: main fused kernel — R13 schedule with blend fused into the MFMA
// scheduling region (rA lifetime preserved: blend consumes rA BEFORE
// issueA(t+2) overwrites it). Per step:
//   vmcnt(4) -> { setprio; MFMA(tt); blend(t+1); setprio(0) } ->
//   issueA/B(t+2) -> vmcnt(12) -> lgkm0 -> barrier.
// Counted vmcnt, never 0 in loop (except tt=34 drain); B tri-buffered.
// block = 128 px x 256 O, 512 thr, 8 waves (wave = 64px x 64o, acc[4][4]).
// ---------------------------------------------------------------------------
union ArenaM {
  struct {
    unsigned short A[2][128][64];   //  32,768 B (byte ^= (row&7)<<4)
    unsigned short Bt[3][16384];    //  98,304 B ([256 o][64 kk] swz)
  } m;
  unsigned short ytile[256][136];   //  69,632 B (o-major epilogue buffer)
};

__global__ __launch_bounds__(512) void dcn_main(
    const unsigned short* __restrict__ xT, const float* __restrict__ offs,
    const float* __restrict__ boff, const unsigned short* __restrict__ wT4,
    unsigned short* __restrict__ yb, float* __restrict__ stats) {
  __shared__ ArenaM ar;
  __shared__ u32 pcor[9][128][2];   //  9,216 B (c01, c23 per (k,px))
  __shared__ float pwt[9][128][4];  // 18,432 B (4 bilinear weights)

  const int bx = blockIdx.x;
  const int lb = ((bx & 7) << 5) + (bx >> 3);   // XCD x -> image x
  const int b = lb >> 5;
  const int pxbase = (lb & 31) << 7;            // 128-px group (2 rows)
  const int t = threadIdx.x;
  const int lane = t & 63, wid = t >> 6;        // wid 0..7
  const char* xTbB = (const char*)xT + ((size_t)b << 21);
  const int pxs = ((wid & 1) << 6) + lane;      // staging px (lane-consec)
  const int gp = (wid >> 1) << 1;               // granules gp, gp+1
  const int wr = wid >> 2, wc = wid & 3;
  const int obase = wc << 6;

  // --- prologue: per-(k,px) sampling params into LDS ---
  for (int idx = t; idx < 1152; idx += 512) {
    int k = idx >> 7, px = idx & 127;
    int pxg = pxbase + px;
    int yy = pxg >> 6, xx = pxg & 63;
    int ky = k / 3, kx = k - ky * 3;
    const float* op = offs + ((size_t)b * 4096 + pxg) * 18 + k * 2;
    float py = op[0] + boff[k * 2] + (float)(yy - 1 + ky);
    float pxf = op[1] + boff[k * 2 + 1] + (float)(xx - 1 + kx);
    float fy = floorf(py), fx = floorf(pxf);
    float dy = py - fy, dx = pxf - fx;
    int y0 = (int)fy, x0 = (int)fx;
    int y1 = y0 + 1, x1 = x0 + 1;
    float vy0 = ((unsigned)y0 < 64u) ? 1.f : 0.f;
    float vy1 = ((unsigned)y1 < 64u) ? 1.f : 0.f;
    float vx0 = ((unsigned)x0 < 64u) ? 1.f : 0.f;
    float vx1 = ((unsigned)x1 < 64u) ? 1.f : 0.f;
    int y0c = min(max(y0, 0), 63), y1c = min(max(y1, 0), 63);
    int x0c = min(max(x0, 0), 63), x1c = min(max(x1, 0), 63);
    pcor[k][px][0] = (u32)((y0c << 6) + x0c) | ((u32)((y0c << 6) + x1c) << 16);
    pcor[k][px][1] = (u32)((y1c << 6) + x0c) | ((u32)((y1c << 6) + x1c) << 16);
    pwt[k][px][0] = (1.f - dy) * (1.f - dx) * vy0 * vx0;
    pwt[k][px][1] = (1.f - dy) * dx * vy0 * vx1;
    pwt[k][px][2] = dy * (1.f - dx) * vy1 * vx0;
    pwt[k][px][3] = dy * dx * vy1 * vx1;
  }

  f32x4 acc[4][4];
#pragma unroll
  for (int i = 0; i < 4; ++i)
#pragma unroll
    for (int j = 0; j < 4; ++j) {
      f32x4 z = {0.f, 0.f, 0.f, 0.f};
      acc[i][j] = z;
    }

  __syncthreads();                 // params ready

  u32x4 rA[8];                     // in-flight corners: 2 granules x 4 corners

  auto issueA = [&](int tt) {      // 8 VMEM loads, coalesced
    int k = tt >> 2, cc = tt & 3;
    u32 c01 = pcor[k][pxs][0], c23 = pcor[k][pxs][1];
    const char* p0 = xTbB + ((size_t)((cc << 3) + gp) << 16);
#pragma unroll
    for (int g = 0; g < 2; ++g) {
      const char* bgp = p0 + ((size_t)g << 16);
      rA[g * 4 + 0] = *(const u32x4*)(bgp + ((size_t)(c01 & 0xffffu) << 4));
      rA[g * 4 + 1] = *(const u32x4*)(bgp + ((size_t)(c01 >> 16) << 4));
      rA[g * 4 + 2] = *(const u32x4*)(bgp + ((size_t)(c23 & 0xffffu) << 4));
      rA[g * 4 + 3] = *(const u32x4*)(bgp + ((size_t)(c23 >> 16) << 4));
    }
  };
  auto issueB = [&](int tt, int bufi) {   // 4 gload_lds, 4KB slice per wave
    const char* src = (const char*)wT4 + ((size_t)tt << 15) + (wid << 12);
    char* dstb = (char*)&ar.m.Bt[bufi][0] + (wid << 12);
#pragma unroll
    for (int i2 = 0; i2 < 4; ++i2) {
      __builtin_amdgcn_global_load_lds(
          (const __attribute__((address_space(1))) u32*)(src + (i2 << 10) + (lane << 4)),
          (__attribute__((address_space(3))) u32*)(dstb + (i2 << 10)),
          16, 0, 0);
    }
  };
  auto blendA = [&](int tt) {      // blend rA -> bf16, swizzled ds_write
    int k = tt >> 2;
    f32x4 w = *(const f32x4*)&pwt[k][pxs][0];
    char* dst = (char*)&ar.m.A[tt & 1][0][0] + pxs * 128;
    int sw = (pxs & 7) << 4;
#pragma unroll
    for (int g = 0; g < 2; ++g) {
      u32 o4[4];
#pragma unroll
      for (int e = 0; e < 4; ++e) {
        u32 u0 = rA[g * 4 + 0][e], u1 = rA[g * 4 + 1][e];
        u32 u2 = rA[g * 4 + 2][e], u3 = rA[g * 4 + 3][e];
        float lo = w[0] * __uint_as_float(u0 << 16);
        lo = fmaf(w[1], __uint_as_float(u1 << 16), lo);
        lo = fmaf(w[2], __uint_as_float(u2 << 16), lo);
        lo = fmaf(w[3], __uint_as_float(u3 << 16), lo);
        float hi = w[0] * __uint_as_float(u0 & 0xffff0000u);
        hi = fmaf(w[1], __uint_as_float(u1 & 0xffff0000u), hi);
        hi = fmaf(w[2], __uint_as_float(u2 & 0xffff0000u), hi);
        hi = fmaf(w[3], __uint_as_float(u3 & 0xffff0000u), hi);
        asm("v_cvt_pk_bf16_f32 %0, %1, %2" : "=v"(o4[e]) : "v"(lo), "v"(hi));
      }
      u32x4 ov = {o4[0], o4[1], o4[2], o4[3]};
      *(u32x4*)(dst + (((gp + g) << 4) ^ sw)) = ov;
    }
  };

  // --- pipeline prologue ---
  issueA(0); FENCE();
  issueB(0, 0); FENCE();
  VMCNT(4);                        // A(0) done (B(0) may fly)
  blendA(0);
  FENCE();
  issueA(1); FENCE();
  issueB(1, 1); FENCE();
  VMCNT(12);                       // own B(0) landed
  LGKM0();
  __builtin_amdgcn_s_barrier();
  FENCE();

  int bm3 = 0;                     // tt % 3
  for (int tt = 0; tt < 36; ++tt) {
    // --- top-of-step: A(t+1) landed (B(t+1)'s 4 loads may stay in flight) ---
    if (tt < 35) { VMCNT(4); }
    // --- MFMA(tt) + blend(t+1) in ONE scheduling region; blend consumes rA
    //     BEFORE any reissue (issueA(t+2) comes after this region) ---
    {
      const char* Ab = (const char*)&ar.m.A[tt & 1][0][0];
      const char* Bb = (const char*)&ar.m.Bt[bm3][0];
      __builtin_amdgcn_s_setprio(1);
#pragma unroll
      for (int s = 0; s < 2; ++s) {
        int kx = (s << 6) + ((lane >> 4) << 4);
        bf16x8 a[4], bb[4];
#pragma unroll
        for (int i = 0; i < 4; ++i) {
          int r16 = (wr << 6) + (i << 4) + (lane & 15);
          a[i] = *(const bf16x8*)(Ab + r16 * 128 + (kx ^ ((r16 & 7) << 4)));
        }
#pragma unroll
        for (int j = 0; j < 4; ++j) {
          int o = obase + (j << 4) + (lane & 15);
          bb[j] = *(const bf16x8*)(Bb + o * 128 + (kx ^ ((o & 7) << 4)));
        }
#pragma unroll
        for (int i = 0; i < 4; ++i)
#pragma unroll
          for (int j = 0; j < 4; ++j)
            acc[i][j] = __builtin_amdgcn_mfma_f32_16x16x32_bf16(a[i], bb[j], acc[i][j], 0, 0, 0);
      }
      if (tt < 35) blendA(tt + 1);   // same region: fills MFMA issue shadow
      __builtin_amdgcn_s_setprio(0);
    }
    FENCE();
    // --- issue t+2 loads (rA now dead until next consume) ---
    if (tt < 34) {
      issueA(tt + 2); FENCE();
      int bn = bm3 + 2; if (bn >= 3) bn -= 3;
      issueB(tt + 2, bn); FENCE();
    }
    if (tt == 34) { VMCNT(0); }    // force B(35) before last barrier
    else { VMCNT(12); }            // own B(tt+1) landed; keep t+2 in flight
    LGKM0();
    __builtin_amdgcn_s_barrier();
    FENCE();
    bm3 = (bm3 == 2) ? 0 : bm3 + 1;
  }

  // --- GroupNorm partial sums (D: col=lane&15 -> o, row=(lane>>4)*4+r -> px) ---
#pragma unroll
  for (int j = 0; j < 4; ++j) {
    float s1 = 0.f, s2 = 0.f;
#pragma unroll
    for (int i = 0; i < 4; ++i)
#pragma unroll
      for (int r = 0; r < 4; ++r) {
        float v = acc[i][j][r];
        s1 += v;
        s2 += v * v;
      }
    s1 += __shfl_xor(s1, 1, 64);  s2 += __shfl_xor(s2, 1, 64);
    s1 += __shfl_xor(s1, 2, 64);  s2 += __shfl_xor(s2, 2, 64);
    s1 += __shfl_xor(s1, 4, 64);  s2 += __shfl_xor(s2, 4, 64);
    s1 += __shfl_xor(s1, 16, 64); s2 += __shfl_xor(s2, 16, 64);
    s1 += __shfl_xor(s1, 32, 64); s2 += __shfl_xor(s2, 32, 64);
    if ((lane & 0x37) == 0) {     // lanes 0 and 8: one per 8-channel group
      int g = (obase + (j << 4) + (lane & 15)) >> 3;
      atomicAdd(&stats[((b << 5) + g) * 2 + 0], s1);
      atomicAdd(&stats[((b << 5) + g) * 2 + 1], s2);
    }
  }

  // --- acc -> ytile[o][px] bf16 -> yb[b][o][px] ---
#pragma unroll
  for (int i = 0; i < 4; ++i)
#pragma unroll
    for (int j = 0; j < 4; ++j) {
      int o = obase + (j << 4) + (lane & 15);
      int pxr = (wr << 6) + (i << 4) + ((lane >> 4) << 2);
      u32 wv0, wv1;
      asm("v_cvt_pk_bf16_f32 %0, %1, %2" : "=v"(wv0) : "v"(acc[i][j][0]), "v"(acc[i][j][1]));
      asm("v_cvt_pk_bf16_f32 %0, %1, %2" : "=v"(wv1) : "v"(acc[i][j][2]), "v"(acc[i][j][3]));
      u32x2 wv = {wv0, wv1};
      *(u32x2*)((char*)ar.ytile + o * 272 + pxr * 2) = wv;
    }
  __syncthreads();
  {
    int o = t >> 1, half = t & 1;
    const char* srcb = (const char*)ar.ytile + o * 272 + (half << 7);
    unsigned short* dst = yb + (((size_t)(b * 256 + o)) << 12) + pxbase + (half << 6);
#pragma unroll
    for (int qq = 0; qq < 8; ++qq)
      *(u32x4*)((char*)dst + (qq << 4)) = *(const u32x4*)(srcb + (qq << 4));
  }
}

// ---------------------------------------------------------------------------
// K5: GroupNorm finalize + Mish — pure streaming.
// ---------------------------------------------------------------------------
__global__ __launch_bounds__(256) void gn_mish(const unsigned short* __restrict__ yb,
                                               const float* __restrict__ stats,
                                               const float* __restrict__ gamma,
                                               const float* __restrict__ beta,
                                               float* __restrict__ out) {
  int v = blockIdx.x * 512 + threadIdx.x;
#pragma unroll
  for (int it = 0; it < 2; ++it, v += 256) {
    int o = (v >> 9) & 255;
    int b = v >> 17;
    float s1 = stats[((b << 5) + (o >> 3)) * 2 + 0];
    float s2 = stats[((b << 5) + (o >> 3)) * 2 + 1];
    float mean = s1 * (1.f / 32768.f);
    float var = s2 * (1.f / 32768.f) - mean * mean;
    float rstd = rsqrtf(var + 1e-5f);
    float ga = gamma[o] * rstd, be = beta[o] - mean * gamma[o] * rstd;
    u32x4 u = *(const u32x4*)(yb + ((size_t)v << 3));
    float res[8];
#pragma unroll
    for (int e = 0; e < 4; ++e) {
      float va = __uint_as_float(u[e] << 16);
      float vb = __uint_as_float(u[e] & 0xffff0000u);
      float v0 = fmaf(va, ga, be);
      float v1 = fmaf(vb, ga, be);
      float e0 = expf(fminf(v0, 15.f));
      float e1 = expf(fminf(v1, 15.f));
      float n0 = e0 * (e0 + 2.f);
      float n1 = e1 * (e1 + 2.f);
      float m0 = v0 * (n0 / (n0 + 2.f));
      float m1 = v1 * (n1 / (n1 + 2.f));
      if (v0 > 15.f) m0 = v0;
      if (v1 > 15.f) m1 = v1;
      res[2 * e] = m0;
      res[2 * e + 1] = m1;
    }
    f32x4 o0 = {res[0], res[1], res[2], res[3]};
    f32x4 o1 = {res[4], res[5], res[6], res[7]};
    float* dst = out + ((size_t)v << 3);
    *(f32x4*)dst = o0;
    *((f32x4*)dst + 1) = o1;
  }
}

// ---------------------------------------------------------------------------
extern "C" void kernel_launch(void* const* d_in, const int* in_sizes, int n_in,
                              void* d_out, int out_size, void* d_ws, size_t ws_size,
                              hipStream_t stream) {
  const float* x     = (const float*)d_in[0];
  const float* w_off = (const float*)d_in[1];
  const float* b_off = (const float*)d_in[2];
  const float* w_dcn = (const float*)d_in[3];
  const float* gamma = (const float*)d_in[4];
  const float* beta  = (const float*)d_in[5];
  float* out = (float*)d_out;
  char* ws = (char*)d_ws;
  unsigned short* xT   = (unsigned short*)(ws);              // 16,777,216 B (bf16)
  unsigned short* yb   = (unsigned short*)(ws + 16777216);   // 16,777,216 B (bf16)
  float* offs          = (float*)(ws + 33554432);            //  2,359,296 B
  unsigned short* wT4  = (unsigned short*)(ws + 35913728);   //  1,179,648 B
  unsigned short* wOffT= (unsigned short*)(ws + 37093376);   //    147,456 B
  float* stats         = (float*)(ws + 37240832);            //      2,048 B
  prep<<<dim3(2594), dim3(256), 0, stream>>>(w_dcn, w_off, wT4, wOffT, stats);
  transpose_x<<<dim3(2048), dim3(256), 0, stream>>>(x, xT);
  conv_offset_mfma<<<dim3(512), dim3(256), 0, stream>>>(xT, wOffT, offs);
  dcn_main<<<dim3(256), dim3(512), 0, stream>>>(xT, offs, b_off, wT4, yb, stats);
  gn_mish<<<dim3(2048), dim3(256), 0, stream>>>(yb, stats, gamma, beta, out);
}